// Round 2
// baseline (85069.580 us; speedup 1.0000x reference)
//
#include <hip/hip_runtime.h>
#include <hip/hip_bf16.h>
#include <math.h>

#define B_ 16
#define T_ 1024
#define F_ 257
#define H_ 512
#define BT (B_*T_)
#define ALEN 128
#define LSTM_NWG 256

// ---- workspace layout (float offsets) ---- total ~96.1 MiB
// A: xf_t -> qs -> c ; B: k -> enh ; C: q
static const size_t OFF_A   = 0;
static const size_t OFF_B   = OFF_A + (size_t)BT*H_;
static const size_t OFF_C   = OFF_B + (size_t)BT*H_;
static const size_t OFF_HB  = OFF_C + (size_t)BT*H_;   // 2 lstm * 2 buf * 8192
static const size_t OFF_CNT = OFF_HB + 32768;          // 1024 ints
static const size_t WS_NEED = OFF_CNT + 1024;          // floats

__device__ __forceinline__ float sigmoidf_(float v) { return 1.0f / (1.0f + expf(-v)); }

// ---------------- generic f32 GEMM: C = act(A @ W^T + bias1 (+bias2)) ----------------
// A row m: k<K1 from A1[m*K1+k], else A2[m*(K-K1)+(k-K1)].  W is [N][K].
// ACT: 0 none, 1 tanh, 2 sigmoid * xmul[m*N+n], 3 none + transposed store C[t][n][b]
template<int ACT>
__global__ __launch_bounds__(256)
void gemm_kernel(const float* __restrict__ A1, const float* __restrict__ A2, int K1,
                 const float* __restrict__ W, const float* __restrict__ bias1,
                 const float* __restrict__ bias2, const float* __restrict__ xmul,
                 float* __restrict__ C, int M, int N, int K)
{
    __shared__ __align__(16) float As[16][68];
    __shared__ __align__(16) float Ws[16][68];
    int tid = threadIdx.x;
    int tx = tid & 15, ty = tid >> 4;
    int m0 = blockIdx.y * 64, n0 = blockIdx.x * 64;
    int lrow = tid >> 2, lk = (tid & 3) * 4;
    float acc[4][4] = {};
    int ntiles = (K + 15) >> 4;
    int ldA2 = K - K1;
    for (int kt = 0; kt < ntiles; ++kt) {
        int k0 = kt << 4;
        #pragma unroll
        for (int j = 0; j < 4; ++j) {
            int k = k0 + lk + j;
            float av = 0.0f, wv = 0.0f;
            if (k < K) {
                int m = m0 + lrow;
                av = (k < K1) ? A1[(size_t)m * K1 + k] : A2[(size_t)m * ldA2 + (k - K1)];
                int n = n0 + lrow;
                if (n < N) wv = W[(size_t)n * K + k];
            }
            As[lk + j][lrow] = av;
            Ws[lk + j][lrow] = wv;
        }
        __syncthreads();
        #pragma unroll
        for (int kk = 0; kk < 16; ++kk) {
            float4 a = *(const float4*)&As[kk][ty * 4];
            float4 w = *(const float4*)&Ws[kk][tx * 4];
            acc[0][0] += a.x * w.x; acc[0][1] += a.x * w.y; acc[0][2] += a.x * w.z; acc[0][3] += a.x * w.w;
            acc[1][0] += a.y * w.x; acc[1][1] += a.y * w.y; acc[1][2] += a.y * w.z; acc[1][3] += a.y * w.w;
            acc[2][0] += a.z * w.x; acc[2][1] += a.z * w.y; acc[2][2] += a.z * w.z; acc[2][3] += a.z * w.w;
            acc[3][0] += a.w * w.x; acc[3][1] += a.w * w.y; acc[3][2] += a.w * w.z; acc[3][3] += a.w * w.w;
        }
        __syncthreads();
    }
    #pragma unroll
    for (int i = 0; i < 4; ++i) {
        int m = m0 + ty * 4 + i;
        #pragma unroll
        for (int j = 0; j < 4; ++j) {
            int n = n0 + tx * 4 + j;
            if (n < N) {
                float v = acc[i][j];
                if (bias1) v += bias1[n];
                if (bias2) v += bias2[n];
                if (ACT == 1) v = tanhf(v);
                if (ACT == 2) v = sigmoidf_(v) * xmul[(size_t)m * N + n];
                if (ACT == 3) {
                    // xf_t[t][n][b]: t = m%1024, b = m/1024  (16 per-line stores merge in L2)
                    C[((size_t)(m & 1023) << 13) + ((size_t)n << 4) + (m >> 10)] = v;
                } else {
                    C[(size_t)m * N + n] = v;
                }
            }
        }
    }
}

// ---------------- persistent fused LSTM (w_ih GEMM fused into recurrence) ----------------
// 256 WGs x 512 thr (8 waves), 1 WG/CU. WG: lstm = wg>>7, 4 units, 4 gates, 16 batches,
// concat k = 1024 (xf 512 | h 512). Wave wv: k-slice [wv*128,+128) (wv<4: w_ih, wv>=4: w_hh).
// Lane: cg = unit_local (4 gate cols), bg = batch quad, ks = 32-k sub-slice.
// Per lane: 32 float4 weights (128 VGPR), reads 512 B LDS/step. Global h double-buffer +
// one device-scope atomic barrier per step.
__global__ __launch_bounds__(512, 2)
void lstm_fused(const float* __restrict__ xf_t,
                const float* __restrict__ k_wih, const float* __restrict__ k_whh,
                const float* __restrict__ k_bih, const float* __restrict__ k_bhh,
                const float* __restrict__ q_wih, const float* __restrict__ q_whh,
                const float* __restrict__ q_bih, const float* __restrict__ q_bhh,
                float* __restrict__ k_out, float* __restrict__ q_out,
                float* __restrict__ hbuf, int* __restrict__ cnt)
{
    const int wg = blockIdx.x, tid = threadIdx.x;
    const int lstm = wg >> 7;
    const int u0 = (wg & 127) * 4;
    const float* wih = lstm ? q_wih : k_wih;
    const float* whh = lstm ? q_whh : k_whh;
    const float* bih = lstm ? q_bih : k_bih;
    const float* bhh = lstm ? q_bhh : k_bhh;
    float* out = lstm ? q_out : k_out;
    float* hb = hbuf + lstm * 16384;

    const int wv = tid >> 6, lane = tid & 63;
    const int cg = lane & 3, bg = (lane >> 2) & 3, ks = lane >> 4;

    float4 wreg[4][8];          // [gate][k-quad]
    {
        const float* Wsrc = (wv < 4) ? wih : whh;
        const int kbase = (wv & 3) * 128 + ks * 32;
        #pragma unroll
        for (int j = 0; j < 4; ++j) {
            const float4* wp = (const float4*)(Wsrc + ((size_t)(j * 512 + u0 + cg) << 9) + kbase);
            #pragma unroll
            for (int i = 0; i < 8; ++i) wreg[j][i] = wp[i];
        }
    }

    __shared__ __align__(16) float vec[16384];   // concat(xf_t, h) as [k][batch], 64 KB
    __shared__ float part[16][16][33];           // [col][batch][wv*4+ks], pad->~4-way max
    __shared__ float gsum[256];                  // [col][batch] reduced

    const int cu = tid & 3, cb = tid >> 2;       // gate-thread mapping (tid<64)
    float bI = 0.f, bF = 0.f, bG = 0.f, bO = 0.f, cst = 0.f;
    if (tid < 64) {
        bI = bih[0 * 512 + u0 + cu] + bhh[0 * 512 + u0 + cu];
        bF = bih[1 * 512 + u0 + cu] + bhh[1 * 512 + u0 + cu];
        bG = bih[2 * 512 + u0 + cu] + bhh[2 * 512 + u0 + cu];
        bO = bih[3 * 512 + u0 + cu] + bhh[3 * 512 + u0 + cu];
    }

    for (int t = 0; t < T_; ++t) {
        const int rb = t & 1;
        __threadfence();   // acquire: stale-line invalidate before reading hb (cross-XCD)
        {
            float4* vd = (float4*)vec;
            const float4* xs = (const float4*)(xf_t + ((size_t)t << 13));
            const float4* hs = (const float4*)(hb + rb * 8192);
            #pragma unroll
            for (int r = 0; r < 4; ++r) vd[r * 512 + tid] = xs[r * 512 + tid];
            #pragma unroll
            for (int r = 0; r < 4; ++r) vd[2048 + r * 512 + tid] = hs[r * 512 + tid];
        }
        __syncthreads();

        float4 a0 = {0,0,0,0}, a1 = {0,0,0,0}, a2 = {0,0,0,0}, a3 = {0,0,0,0};
        {
            const float4* vb = ((const float4*)vec) + (((size_t)wv * 128 + ks * 32) << 2) + bg;
            #pragma unroll
            for (int i = 0; i < 8; ++i) {
                float4 v0 = vb[(i * 4 + 0) * 4];
                float4 v1 = vb[(i * 4 + 1) * 4];
                float4 v2 = vb[(i * 4 + 2) * 4];
                float4 v3 = vb[(i * 4 + 3) * 4];
                float4 w;
                #define FMA4_(A) \
                    A.x += w.x * v0.x + w.y * v1.x + w.z * v2.x + w.w * v3.x; \
                    A.y += w.x * v0.y + w.y * v1.y + w.z * v2.y + w.w * v3.y; \
                    A.z += w.x * v0.z + w.y * v1.z + w.z * v2.z + w.w * v3.z; \
                    A.w += w.x * v0.w + w.y * v1.w + w.z * v2.w + w.w * v3.w;
                w = wreg[0][i]; FMA4_(a0)
                w = wreg[1][i]; FMA4_(a1)
                w = wreg[2][i]; FMA4_(a2)
                w = wreg[3][i]; FMA4_(a3)
                #undef FMA4_
            }
        }
        {
            const int s = wv * 4 + ks, c0 = cg * 4, bq = bg * 4;
            part[c0 + 0][bq + 0][s] = a0.x; part[c0 + 0][bq + 1][s] = a0.y;
            part[c0 + 0][bq + 2][s] = a0.z; part[c0 + 0][bq + 3][s] = a0.w;
            part[c0 + 1][bq + 0][s] = a1.x; part[c0 + 1][bq + 1][s] = a1.y;
            part[c0 + 1][bq + 2][s] = a1.z; part[c0 + 1][bq + 3][s] = a1.w;
            part[c0 + 2][bq + 0][s] = a2.x; part[c0 + 2][bq + 1][s] = a2.y;
            part[c0 + 2][bq + 2][s] = a2.z; part[c0 + 2][bq + 3][s] = a2.w;
            part[c0 + 3][bq + 0][s] = a3.x; part[c0 + 3][bq + 1][s] = a3.y;
            part[c0 + 3][bq + 2][s] = a3.z; part[c0 + 3][bq + 3][s] = a3.w;
        }
        __syncthreads();

        if (tid < 256) {            // 2-phase reduce: 4 waves sum 32 partials each
            const int c = tid >> 4, b = tid & 15;
            float s = 0.f;
            #pragma unroll
            for (int ss = 0; ss < 32; ++ss) s += part[c][b][ss];
            gsum[c * 16 + b] = s;   // bank = (tid + ss)%32 pattern on reads: conflict-free-ish
        }
        __syncthreads();

        if (tid < 64) {
            float gI = bI + gsum[(cu * 4 + 0) * 16 + cb];
            float gF = bF + gsum[(cu * 4 + 1) * 16 + cb];
            float gG = bG + gsum[(cu * 4 + 2) * 16 + cb];
            float gO = bO + gsum[(cu * 4 + 3) * 16 + cb];
            float ig = sigmoidf_(gI), fg = sigmoidf_(gF), gg = tanhf(gG), og = sigmoidf_(gO);
            cst = fg * cst + ig * gg;
            float h = og * tanhf(cst);
            hb[(rb ^ 1) * 8192 + ((u0 + cu) << 4) + cb] = h;
            out[((size_t)(cb * T_ + t) << 9) + (u0 + cu)] = h;
        }
        __threadfence();   // release: drain h stores to device coherence point
        __syncthreads();
        if (tid == 0) {
            __hip_atomic_fetch_add(&cnt[t], 1, __ATOMIC_RELEASE, __HIP_MEMORY_SCOPE_AGENT);
            while (__hip_atomic_load(&cnt[t], __ATOMIC_ACQUIRE, __HIP_MEMORY_SCOPE_AGENT) < LSTM_NWG)
                __builtin_amdgcn_s_sleep(2);
        }
        __syncthreads();
    }
}

// ---------------- attention pass 1: banded causal exp-scores -> normalized rows ----------------
__global__ __launch_bounds__(256)
void attn_scores(const float* __restrict__ qs, const float* __restrict__ kk,
                 float* __restrict__ attn_out)
{
    int t = blockIdx.x, b = blockIdx.y, tid = threadIdx.x;
    int jlo = t - ALEN; if (jlo < 0) jlo = 0;
    int cnt = t - jlo + 1;                       // <= 129
    __shared__ __align__(16) float qrow[512];
    __shared__ float sc[132];
    __shared__ float ssum;
    const float* qsr = qs + ((size_t)(b * T_ + t) << 9);
    qrow[tid] = qsr[tid];
    qrow[tid + 256] = qsr[tid + 256];
    __syncthreads();
    if (tid < cnt) {
        const float4* krow = (const float4*)(kk + ((size_t)(b * T_ + jlo + tid) << 9));
        const float4* q4 = (const float4*)qrow;
        float acc = 0.f;
        #pragma unroll 4
        for (int i = 0; i < 128; ++i) {
            float4 kv = krow[i]; float4 qv = q4[i];
            acc += kv.x * qv.x + kv.y * qv.y + kv.z * qv.z + kv.w * qv.w;
        }
        sc[tid] = expf(acc);                     // no max-subtraction (faithful to reference)
    }
    __syncthreads();
    if (tid < 64) {
        float s = 0.f;
        for (int j = tid; j < cnt; j += 64) s += sc[j];
        #pragma unroll
        for (int off = 32; off > 0; off >>= 1) s += __shfl_down(s, off);
        if (tid == 0) ssum = s + 1e-10f;
    }
    __syncthreads();
    float inv = 1.0f / ssum;
    // full row incl. zeros outside band (d_out is poisoned pre-launch)
    float4* arow = (float4*)(attn_out + ((size_t)(b * T_ + t) << 10));
    int j0 = tid * 4;
    float4 v;
    v.x = (j0 + 0 >= jlo && j0 + 0 <= t) ? sc[j0 + 0 - jlo] * inv : 0.f;
    v.y = (j0 + 1 >= jlo && j0 + 1 <= t) ? sc[j0 + 1 - jlo] * inv : 0.f;
    v.z = (j0 + 2 >= jlo && j0 + 2 <= t) ? sc[j0 + 2 - jlo] * inv : 0.f;
    v.w = (j0 + 3 >= jlo && j0 + 3 <= t) ? sc[j0 + 3 - jlo] * inv : 0.f;
    arow[tid] = v;
}

// ---------------- attention pass 2: c = attn(normalized rows) @ k ----------------
__global__ __launch_bounds__(256)
void attn_ctx(const float* __restrict__ attn, const float* __restrict__ kk,
              float* __restrict__ c_out)
{
    int t = blockIdx.x, b = blockIdx.y, tid = threadIdx.x;
    int jlo = t - ALEN; if (jlo < 0) jlo = 0;
    int cnt = t - jlo + 1;
    __shared__ float sc[132];
    if (tid < cnt) sc[tid] = attn[((size_t)(b * T_ + t) << 10) + jlo + tid];
    __syncthreads();
    #pragma unroll
    for (int hh = 0; hh < 2; ++hh) {
        int h = tid + hh * 256;
        const float* kcol = kk + ((size_t)(b * T_ + jlo) << 9) + h;
        float acc = 0.f;
        #pragma unroll 4
        for (int jj = 0; jj < cnt; ++jj) acc += sc[jj] * kcol[(size_t)jj << 9];
        c_out[((size_t)(b * T_ + t) << 9) + h] = acc;
    }
}

extern "C" void kernel_launch(void* const* d_in, const int* in_sizes, int n_in,
                              void* d_out_v, int out_size, void* d_ws, size_t ws_size,
                              hipStream_t stream)
{
    const float* x       = (const float*)d_in[0];
    const float* feat_w  = (const float*)d_in[1];
    const float* feat_b  = (const float*)d_in[2];
    const float* k_w_ih  = (const float*)d_in[3];
    const float* k_w_hh  = (const float*)d_in[4];
    const float* k_b_ih  = (const float*)d_in[5];
    const float* k_b_hh  = (const float*)d_in[6];
    const float* q_w_ih  = (const float*)d_in[7];
    const float* q_w_hh  = (const float*)d_in[8];
    const float* q_b_ih  = (const float*)d_in[9];
    const float* q_b_hh  = (const float*)d_in[10];
    const float* score_w = (const float*)d_in[11];
    const float* enh_w   = (const float*)d_in[12];
    const float* enh_b   = (const float*)d_in[13];
    const float* mask_w  = (const float*)d_in[14];
    const float* mask_b  = (const float*)d_in[15];
    float* out = (float*)d_out_v;
    float* ws  = (float*)d_ws;

    if (ws_size < WS_NEED * sizeof(float)) return;  // clean fail (not a GPU fault) if ws too small

    float* bufA = ws + OFF_A;   // xf_t -> qs -> c
    float* bufB = ws + OFF_B;   // k -> enh
    float* bufC = ws + OFF_C;   // q
    float* hbuf = ws + OFF_HB;
    int*   cnt  = (int*)(ws + OFF_CNT);

    hipMemsetAsync(hbuf, 0, (32768 + 1024) * sizeof(float), stream);

    dim3 blk(256);
    // xf_t[t][n][b] = x @ feat_w^T + feat_b   (transposed store for LSTM staging)
    gemm_kernel<3><<<dim3(8, 256), blk, 0, stream>>>(x, nullptr, F_, feat_w, feat_b, nullptr, nullptr, bufA, BT, H_, F_);
    // fused recurrence, both LSTMs (w_ih + w_hh + biases inside)
    lstm_fused<<<dim3(LSTM_NWG), dim3(512), 0, stream>>>(bufA,
        k_w_ih, k_w_hh, k_b_ih, k_b_hh, q_w_ih, q_w_hh, q_b_ih, q_b_hh,
        bufB, bufC, hbuf, cnt);
    // qs = q @ score_w^T  (overwrites xf_t, dead)
    gemm_kernel<0><<<dim3(8, 256), blk, 0, stream>>>(bufC, nullptr, H_, score_w, nullptr, nullptr, nullptr, bufA, BT, H_, H_);
    // attn rows -> d_out tail
    attn_scores<<<dim3(T_, B_), blk, 0, stream>>>(bufA, bufB, out + (size_t)BT * F_);
    // c = attn @ k  (overwrites qs, dead)
    attn_ctx<<<dim3(T_, B_), blk, 0, stream>>>(out + (size_t)BT * F_, bufB, bufA);
    // enh = tanh(concat(c, q) @ enh_w^T + enh_b)  (overwrites k, dead)
    gemm_kernel<1><<<dim3(8, 256), blk, 0, stream>>>(bufA, bufC, H_, enh_w, enh_b, nullptr, nullptr, bufB, BT, H_, 2 * H_);
    // out = sigmoid(enh @ mask_w^T + mask_b) * x
    gemm_kernel<2><<<dim3(5, 256), blk, 0, stream>>>(bufB, nullptr, H_, mask_w, mask_b, nullptr, x, out, BT, F_, H_);
}

// Round 3
// 10363.804 us; speedup vs baseline: 8.2083x; 8.2083x over previous
//
#include <hip/hip_runtime.h>
#include <hip/hip_bf16.h>
#include <math.h>

#define B_ 16
#define T_ 1024
#define F_ 257
#define H_ 512
#define BT (B_*T_)
#define ALEN 128
#define LSTM_NWG 256

// ---- workspace layout (float offsets) ---- total ~96.1 MiB
// A: xf_t -> qs -> c ; B: k -> enh ; C: q
static const size_t OFF_A   = 0;
static const size_t OFF_B   = OFF_A + (size_t)BT*H_;
static const size_t OFF_C   = OFF_B + (size_t)BT*H_;
static const size_t OFF_HB  = OFF_C + (size_t)BT*H_;   // 2 lstm * 2 buf * 8192
static const size_t OFF_CNT = OFF_HB + 32768;          // 1024 ints
static const size_t WS_NEED = OFF_CNT + 1024;          // floats

__device__ __forceinline__ float sigmoidf_(float v) { return 1.0f / (1.0f + expf(-v)); }

// ---------------- generic f32 GEMM: C = act(A @ W^T + bias1 (+bias2)) ----------------
// A row m: k<K1 from A1[m*K1+k], else A2[m*(K-K1)+(k-K1)].  W is [N][K].
// ACT: 0 none, 1 tanh, 2 sigmoid * xmul[m*N+n], 3 none + transposed store C[t][n][b]
template<int ACT>
__global__ __launch_bounds__(256)
void gemm_kernel(const float* __restrict__ A1, const float* __restrict__ A2, int K1,
                 const float* __restrict__ W, const float* __restrict__ bias1,
                 const float* __restrict__ bias2, const float* __restrict__ xmul,
                 float* __restrict__ C, int M, int N, int K)
{
    __shared__ __align__(16) float As[16][68];
    __shared__ __align__(16) float Ws[16][68];
    int tid = threadIdx.x;
    int tx = tid & 15, ty = tid >> 4;
    int m0 = blockIdx.y * 64, n0 = blockIdx.x * 64;
    int lrow = tid >> 2, lk = (tid & 3) * 4;
    float acc[4][4] = {};
    int ntiles = (K + 15) >> 4;
    int ldA2 = K - K1;
    for (int kt = 0; kt < ntiles; ++kt) {
        int k0 = kt << 4;
        #pragma unroll
        for (int j = 0; j < 4; ++j) {
            int k = k0 + lk + j;
            float av = 0.0f, wv = 0.0f;
            if (k < K) {
                int m = m0 + lrow;
                av = (k < K1) ? A1[(size_t)m * K1 + k] : A2[(size_t)m * ldA2 + (k - K1)];
                int n = n0 + lrow;
                if (n < N) wv = W[(size_t)n * K + k];
            }
            As[lk + j][lrow] = av;
            Ws[lk + j][lrow] = wv;
        }
        __syncthreads();
        #pragma unroll
        for (int kk = 0; kk < 16; ++kk) {
            float4 a = *(const float4*)&As[kk][ty * 4];
            float4 w = *(const float4*)&Ws[kk][tx * 4];
            acc[0][0] += a.x * w.x; acc[0][1] += a.x * w.y; acc[0][2] += a.x * w.z; acc[0][3] += a.x * w.w;
            acc[1][0] += a.y * w.x; acc[1][1] += a.y * w.y; acc[1][2] += a.y * w.z; acc[1][3] += a.y * w.w;
            acc[2][0] += a.z * w.x; acc[2][1] += a.z * w.y; acc[2][2] += a.z * w.z; acc[2][3] += a.z * w.w;
            acc[3][0] += a.w * w.x; acc[3][1] += a.w * w.y; acc[3][2] += a.w * w.z; acc[3][3] += a.w * w.w;
        }
        __syncthreads();
    }
    #pragma unroll
    for (int i = 0; i < 4; ++i) {
        int m = m0 + ty * 4 + i;
        #pragma unroll
        for (int j = 0; j < 4; ++j) {
            int n = n0 + tx * 4 + j;
            if (n < N) {
                float v = acc[i][j];
                if (bias1) v += bias1[n];
                if (bias2) v += bias2[n];
                if (ACT == 1) v = tanhf(v);
                if (ACT == 2) v = sigmoidf_(v) * xmul[(size_t)m * N + n];
                if (ACT == 3) {
                    // xf_t[t][n][b]: t = m%1024, b = m/1024  (16 per-line stores merge in L2)
                    C[((size_t)(m & 1023) << 13) + ((size_t)n << 4) + (m >> 10)] = v;
                } else {
                    C[(size_t)m * N + n] = v;
                }
            }
        }
    }
}

// ---------------- persistent fused LSTM (w_ih GEMM fused into recurrence) ----------------
// 256 WGs x 512 thr (8 waves), 1 WG/CU. WG: lstm = wg>>7, 4 units, 4 gates, 16 batches,
// concat k = 1024 (xf 512 | h 512). Wave wv: k-slice [wv*128,+128) (wv<4: w_ih, wv>=4: w_hh).
// Synchronization design (round-3 fix): NO fences anywhere. h goes through cache-bypassing
// sc0sc1 loads/stores (coherent at L3), barrier via RELAXED atomics (no buffer_inv storms).
// Store->signal ordering via explicit s_waitcnt vmcnt(0) (sc1 store ack = coherence point).
__global__ __launch_bounds__(512, 2)
void lstm_fused(const float* __restrict__ xf_t,
                const float* __restrict__ k_wih, const float* __restrict__ k_whh,
                const float* __restrict__ k_bih, const float* __restrict__ k_bhh,
                const float* __restrict__ q_wih, const float* __restrict__ q_whh,
                const float* __restrict__ q_bih, const float* __restrict__ q_bhh,
                float* __restrict__ k_out, float* __restrict__ q_out,
                float* __restrict__ hbuf, int* __restrict__ cnt)
{
    const int wg = blockIdx.x, tid = threadIdx.x;
    const int lstm = wg >> 7;
    const int u0 = (wg & 127) * 4;
    const float* wih = lstm ? q_wih : k_wih;
    const float* whh = lstm ? q_whh : k_whh;
    const float* bih = lstm ? q_bih : k_bih;
    const float* bhh = lstm ? q_bhh : k_bhh;
    float* out = lstm ? q_out : k_out;
    float* hb = hbuf + lstm * 16384;

    const int wv = tid >> 6, lane = tid & 63;
    const int cg = lane & 3, bg = (lane >> 2) & 3, ks = lane >> 4;

    float4 wreg[4][8];          // [gate][k-quad]
    {
        const float* Wsrc = (wv < 4) ? wih : whh;
        const int kbase = (wv & 3) * 128 + ks * 32;
        #pragma unroll
        for (int j = 0; j < 4; ++j) {
            const float4* wp = (const float4*)(Wsrc + ((size_t)(j * 512 + u0 + cg) << 9) + kbase);
            #pragma unroll
            for (int i = 0; i < 8; ++i) wreg[j][i] = wp[i];
        }
    }

    __shared__ __align__(16) float vec[16384];   // concat(xf_t, h) as [k][batch], 64 KB
    __shared__ float part[16][16][33];           // [col][batch][wv*4+ks]
    __shared__ float gsum[256];                  // [col][batch] reduced

    const int cu = tid & 3, cb = tid >> 2;       // gate-thread mapping (tid<64)
    float bI = 0.f, bF = 0.f, bG = 0.f, bO = 0.f, cst = 0.f;
    if (tid < 64) {
        bI = bih[0 * 512 + u0 + cu] + bhh[0 * 512 + u0 + cu];
        bF = bih[1 * 512 + u0 + cu] + bhh[1 * 512 + u0 + cu];
        bG = bih[2 * 512 + u0 + cu] + bhh[2 * 512 + u0 + cu];
        bO = bih[3 * 512 + u0 + cu] + bhh[3 * 512 + u0 + cu];
    }

    for (int t = 0; t < T_; ++t) {
        const int rb = t & 1;
        {
            float4* vd = (float4*)vec;
            const float4* xs = (const float4*)(xf_t + ((size_t)t << 13));
            #pragma unroll
            for (int r = 0; r < 4; ++r) vd[r * 512 + tid] = xs[r * 512 + tid];
            // h: coherence-point loads (bypass stale L1/L2), 4 in flight then one wait
            const float4* hp = (const float4*)(hb + rb * 8192);
            const float4* p0 = hp + 0 * 512 + tid;
            const float4* p1 = hp + 1 * 512 + tid;
            const float4* p2 = hp + 2 * 512 + tid;
            const float4* p3 = hp + 3 * 512 + tid;
            float4 h0, h1, h2, h3;
            asm volatile(
                "global_load_dwordx4 %0, %4, off sc0 sc1\n\t"
                "global_load_dwordx4 %1, %5, off sc0 sc1\n\t"
                "global_load_dwordx4 %2, %6, off sc0 sc1\n\t"
                "global_load_dwordx4 %3, %7, off sc0 sc1\n\t"
                "s_waitcnt vmcnt(0)"
                : "=&v"(h0), "=&v"(h1), "=&v"(h2), "=&v"(h3)
                : "v"(p0), "v"(p1), "v"(p2), "v"(p3)
                : "memory");
            vd[2048 + 0 * 512 + tid] = h0;
            vd[2048 + 1 * 512 + tid] = h1;
            vd[2048 + 2 * 512 + tid] = h2;
            vd[2048 + 3 * 512 + tid] = h3;
        }
        __syncthreads();

        float4 a0 = {0,0,0,0}, a1 = {0,0,0,0}, a2 = {0,0,0,0}, a3 = {0,0,0,0};
        {
            const float4* vb = ((const float4*)vec) + (((size_t)wv * 128 + ks * 32) << 2) + bg;
            #pragma unroll
            for (int i = 0; i < 8; ++i) {
                float4 v0 = vb[(i * 4 + 0) * 4];
                float4 v1 = vb[(i * 4 + 1) * 4];
                float4 v2 = vb[(i * 4 + 2) * 4];
                float4 v3 = vb[(i * 4 + 3) * 4];
                float4 w;
                #define FMA4_(A) \
                    A.x += w.x * v0.x + w.y * v1.x + w.z * v2.x + w.w * v3.x; \
                    A.y += w.x * v0.y + w.y * v1.y + w.z * v2.y + w.w * v3.y; \
                    A.z += w.x * v0.z + w.y * v1.z + w.z * v2.z + w.w * v3.z; \
                    A.w += w.x * v0.w + w.y * v1.w + w.z * v2.w + w.w * v3.w;
                w = wreg[0][i]; FMA4_(a0)
                w = wreg[1][i]; FMA4_(a1)
                w = wreg[2][i]; FMA4_(a2)
                w = wreg[3][i]; FMA4_(a3)
                #undef FMA4_
            }
        }
        {
            const int s = wv * 4 + ks, c0 = cg * 4, bq = bg * 4;
            part[c0 + 0][bq + 0][s] = a0.x; part[c0 + 0][bq + 1][s] = a0.y;
            part[c0 + 0][bq + 2][s] = a0.z; part[c0 + 0][bq + 3][s] = a0.w;
            part[c0 + 1][bq + 0][s] = a1.x; part[c0 + 1][bq + 1][s] = a1.y;
            part[c0 + 1][bq + 2][s] = a1.z; part[c0 + 1][bq + 3][s] = a1.w;
            part[c0 + 2][bq + 0][s] = a2.x; part[c0 + 2][bq + 1][s] = a2.y;
            part[c0 + 2][bq + 2][s] = a2.z; part[c0 + 2][bq + 3][s] = a2.w;
            part[c0 + 3][bq + 0][s] = a3.x; part[c0 + 3][bq + 1][s] = a3.y;
            part[c0 + 3][bq + 2][s] = a3.z; part[c0 + 3][bq + 3][s] = a3.w;
        }
        __syncthreads();

        if (tid < 256) {            // 2-phase reduce: 4 waves sum 32 partials each
            const int c = tid >> 4, b = tid & 15;
            float s = 0.f;
            #pragma unroll
            for (int ss = 0; ss < 32; ++ss) s += part[c][b][ss];
            gsum[c * 16 + b] = s;
        }
        __syncthreads();

        if (tid < 64) {
            float gI = bI + gsum[(cu * 4 + 0) * 16 + cb];
            float gF = bF + gsum[(cu * 4 + 1) * 16 + cb];
            float gG = bG + gsum[(cu * 4 + 2) * 16 + cb];
            float gO = bO + gsum[(cu * 4 + 3) * 16 + cb];
            float ig = sigmoidf_(gI), fg = sigmoidf_(gF), gg = tanhf(gG), og = sigmoidf_(gO);
            cst = fg * cst + ig * gg;
            float h = og * tanhf(cst);
            // coherence-point store (write-through past L2) — visible to all XCDs once vmcnt retires
            __hip_atomic_store(&hb[(rb ^ 1) * 8192 + ((u0 + cu) << 4) + cb], h,
                               __ATOMIC_RELAXED, __HIP_MEMORY_SCOPE_SYSTEM);
            out[((size_t)(cb * T_ + t) << 9) + (u0 + cu)] = h;
        }
        asm volatile("s_waitcnt vmcnt(0)" ::: "memory");  // h stores acked at coherence point
        __syncthreads();
        if (tid == 0) {
            __hip_atomic_fetch_add(&cnt[t], 1, __ATOMIC_RELAXED, __HIP_MEMORY_SCOPE_AGENT);
            while (__hip_atomic_load(&cnt[t], __ATOMIC_RELAXED, __HIP_MEMORY_SCOPE_SYSTEM) < LSTM_NWG)
                __builtin_amdgcn_s_sleep(4);
        }
        __syncthreads();
    }
}

// ---------------- attention pass 1: banded causal exp-scores -> normalized rows ----------------
__global__ __launch_bounds__(256)
void attn_scores(const float* __restrict__ qs, const float* __restrict__ kk,
                 float* __restrict__ attn_out)
{
    int t = blockIdx.x, b = blockIdx.y, tid = threadIdx.x;
    int jlo = t - ALEN; if (jlo < 0) jlo = 0;
    int cnt = t - jlo + 1;                       // <= 129
    __shared__ __align__(16) float qrow[512];
    __shared__ float sc[132];
    __shared__ float ssum;
    const float* qsr = qs + ((size_t)(b * T_ + t) << 9);
    qrow[tid] = qsr[tid];
    qrow[tid + 256] = qsr[tid + 256];
    __syncthreads();
    if (tid < cnt) {
        const float4* krow = (const float4*)(kk + ((size_t)(b * T_ + jlo + tid) << 9));
        const float4* q4 = (const float4*)qrow;
        float acc = 0.f;
        #pragma unroll 4
        for (int i = 0; i < 128; ++i) {
            float4 kv = krow[i]; float4 qv = q4[i];
            acc += kv.x * qv.x + kv.y * qv.y + kv.z * qv.z + kv.w * qv.w;
        }
        sc[tid] = expf(acc);                     // no max-subtraction (faithful to reference)
    }
    __syncthreads();
    if (tid < 64) {
        float s = 0.f;
        for (int j = tid; j < cnt; j += 64) s += sc[j];
        #pragma unroll
        for (int off = 32; off > 0; off >>= 1) s += __shfl_down(s, off);
        if (tid == 0) ssum = s + 1e-10f;
    }
    __syncthreads();
    float inv = 1.0f / ssum;
    // full row incl. zeros outside band (d_out is poisoned pre-launch)
    float4* arow = (float4*)(attn_out + ((size_t)(b * T_ + t) << 10));
    int j0 = tid * 4;
    float4 v;
    v.x = (j0 + 0 >= jlo && j0 + 0 <= t) ? sc[j0 + 0 - jlo] * inv : 0.f;
    v.y = (j0 + 1 >= jlo && j0 + 1 <= t) ? sc[j0 + 1 - jlo] * inv : 0.f;
    v.z = (j0 + 2 >= jlo && j0 + 2 <= t) ? sc[j0 + 2 - jlo] * inv : 0.f;
    v.w = (j0 + 3 >= jlo && j0 + 3 <= t) ? sc[j0 + 3 - jlo] * inv : 0.f;
    arow[tid] = v;
}

// ---------------- attention pass 2: c = attn(normalized rows) @ k ----------------
__global__ __launch_bounds__(256)
void attn_ctx(const float* __restrict__ attn, const float* __restrict__ kk,
              float* __restrict__ c_out)
{
    int t = blockIdx.x, b = blockIdx.y, tid = threadIdx.x;
    int jlo = t - ALEN; if (jlo < 0) jlo = 0;
    int cnt = t - jlo + 1;
    __shared__ float sc[132];
    if (tid < cnt) sc[tid] = attn[((size_t)(b * T_ + t) << 10) + jlo + tid];
    __syncthreads();
    #pragma unroll
    for (int hh = 0; hh < 2; ++hh) {
        int h = tid + hh * 256;
        const float* kcol = kk + ((size_t)(b * T_ + jlo) << 9) + h;
        float acc = 0.f;
        #pragma unroll 4
        for (int jj = 0; jj < cnt; ++jj) acc += sc[jj] * kcol[(size_t)jj << 9];
        c_out[((size_t)(b * T_ + t) << 9) + h] = acc;
    }
}

extern "C" void kernel_launch(void* const* d_in, const int* in_sizes, int n_in,
                              void* d_out_v, int out_size, void* d_ws, size_t ws_size,
                              hipStream_t stream)
{
    const float* x       = (const float*)d_in[0];
    const float* feat_w  = (const float*)d_in[1];
    const float* feat_b  = (const float*)d_in[2];
    const float* k_w_ih  = (const float*)d_in[3];
    const float* k_w_hh  = (const float*)d_in[4];
    const float* k_b_ih  = (const float*)d_in[5];
    const float* k_b_hh  = (const float*)d_in[6];
    const float* q_w_ih  = (const float*)d_in[7];
    const float* q_w_hh  = (const float*)d_in[8];
    const float* q_b_ih  = (const float*)d_in[9];
    const float* q_b_hh  = (const float*)d_in[10];
    const float* score_w = (const float*)d_in[11];
    const float* enh_w   = (const float*)d_in[12];
    const float* enh_b   = (const float*)d_in[13];
    const float* mask_w  = (const float*)d_in[14];
    const float* mask_b  = (const float*)d_in[15];
    float* out = (float*)d_out_v;
    float* ws  = (float*)d_ws;

    if (ws_size < WS_NEED * sizeof(float)) return;  // clean fail (not a GPU fault) if ws too small

    float* bufA = ws + OFF_A;   // xf_t -> qs -> c
    float* bufB = ws + OFF_B;   // k -> enh
    float* bufC = ws + OFF_C;   // q
    float* hbuf = ws + OFF_HB;
    int*   cnt  = (int*)(ws + OFF_CNT);

    hipMemsetAsync(hbuf, 0, (32768 + 1024) * sizeof(float), stream);

    dim3 blk(256);
    // xf_t[t][n][b] = x @ feat_w^T + feat_b   (transposed store for LSTM staging)
    gemm_kernel<3><<<dim3(8, 256), blk, 0, stream>>>(x, nullptr, F_, feat_w, feat_b, nullptr, nullptr, bufA, BT, H_, F_);
    // fused recurrence, both LSTMs (w_ih + w_hh + biases inside)
    lstm_fused<<<dim3(LSTM_NWG), dim3(512), 0, stream>>>(bufA,
        k_w_ih, k_w_hh, k_b_ih, k_b_hh, q_w_ih, q_w_hh, q_b_ih, q_b_hh,
        bufB, bufC, hbuf, cnt);
    // qs = q @ score_w^T  (overwrites xf_t, dead)
    gemm_kernel<0><<<dim3(8, 256), blk, 0, stream>>>(bufC, nullptr, H_, score_w, nullptr, nullptr, nullptr, bufA, BT, H_, H_);
    // attn rows -> d_out tail
    attn_scores<<<dim3(T_, B_), blk, 0, stream>>>(bufA, bufB, out + (size_t)BT * F_);
    // c = attn @ k  (overwrites qs, dead)
    attn_ctx<<<dim3(T_, B_), blk, 0, stream>>>(out + (size_t)BT * F_, bufB, bufA);
    // enh = tanh(concat(c, q) @ enh_w^T + enh_b)  (overwrites k, dead)
    gemm_kernel<1><<<dim3(8, 256), blk, 0, stream>>>(bufA, bufC, H_, enh_w, enh_b, nullptr, nullptr, bufB, BT, H_, 2 * H_);
    // out = sigmoid(enh @ mask_w^T + mask_b) * x
    gemm_kernel<2><<<dim3(5, 256), blk, 0, stream>>>(bufB, nullptr, H_, mask_w, mask_b, nullptr, x, out, BT, F_, H_);
}

// Round 5
// 8043.951 us; speedup vs baseline: 10.5756x; 1.2884x over previous
//
#include <hip/hip_runtime.h>
#include <hip/hip_bf16.h>
#include <math.h>

#define B_ 16
#define T_ 1024
#define F_ 257
#define H_ 512
#define BT (B_*T_)
#define ALEN 128
#define LSTM_NWG 256

// ---- workspace layout (float offsets) ---- total ~96.2 MiB
// A: xf_t -> qs -> c ; B: k -> enh ; C: q
static const size_t OFF_A    = 0;
static const size_t OFF_B    = OFF_A + (size_t)BT*H_;
static const size_t OFF_C    = OFF_B + (size_t)BT*H_;
static const size_t OFF_HB   = OFF_C + (size_t)BT*H_;   // 2 lstm * 2 buf * 8192 floats
static const size_t OFF_SUB  = OFF_HB + 32768;          // 2*8*1024 ints (group counters)
static const size_t OFF_MST  = OFF_SUB + 16384;         // 2*1024 ints (master counters)
static const size_t WS_NEED  = OFF_MST + 2048;          // floats

__device__ __forceinline__ float sigmoidf_(float v) { return 1.0f / (1.0f + expf(-v)); }

// ---------------- generic f32 GEMM: C = act(A @ W^T + bias1 (+bias2)) ----------------
// A row m: k<K1 from A1[m*K1+k], else A2[m*(K-K1)+(k-K1)].  W is [N][K].
// ACT: 0 none, 1 tanh, 2 sigmoid * xmul[m*N+n], 3 none + transposed store C[t][n][b]
template<int ACT>
__global__ __launch_bounds__(256)
void gemm_kernel(const float* __restrict__ A1, const float* __restrict__ A2, int K1,
                 const float* __restrict__ W, const float* __restrict__ bias1,
                 const float* __restrict__ bias2, const float* __restrict__ xmul,
                 float* __restrict__ C, int M, int N, int K)
{
    __shared__ __align__(16) float As[16][68];
    __shared__ __align__(16) float Ws[16][68];
    int tid = threadIdx.x;
    int tx = tid & 15, ty = tid >> 4;
    int m0 = blockIdx.y * 64, n0 = blockIdx.x * 64;
    int lrow = tid >> 2, lk = (tid & 3) * 4;
    float acc[4][4] = {};
    int ntiles = (K + 15) >> 4;
    int ldA2 = K - K1;
    for (int kt = 0; kt < ntiles; ++kt) {
        int k0 = kt << 4;
        #pragma unroll
        for (int j = 0; j < 4; ++j) {
            int k = k0 + lk + j;
            float av = 0.0f, wv = 0.0f;
            if (k < K) {
                int m = m0 + lrow;
                av = (k < K1) ? A1[(size_t)m * K1 + k] : A2[(size_t)m * ldA2 + (k - K1)];
                int n = n0 + lrow;
                if (n < N) wv = W[(size_t)n * K + k];
            }
            As[lk + j][lrow] = av;
            Ws[lk + j][lrow] = wv;
        }
        __syncthreads();
        #pragma unroll
        for (int kk = 0; kk < 16; ++kk) {
            float4 a = *(const float4*)&As[kk][ty * 4];
            float4 w = *(const float4*)&Ws[kk][tx * 4];
            acc[0][0] += a.x * w.x; acc[0][1] += a.x * w.y; acc[0][2] += a.x * w.z; acc[0][3] += a.x * w.w;
            acc[1][0] += a.y * w.x; acc[1][1] += a.y * w.y; acc[1][2] += a.y * w.z; acc[1][3] += a.y * w.w;
            acc[2][0] += a.z * w.x; acc[2][1] += a.z * w.y; acc[2][2] += a.z * w.z; acc[2][3] += a.z * w.w;
            acc[3][0] += a.w * w.x; acc[3][1] += a.w * w.y; acc[3][2] += a.w * w.z; acc[3][3] += a.w * w.w;
        }
        __syncthreads();
    }
    #pragma unroll
    for (int i = 0; i < 4; ++i) {
        int m = m0 + ty * 4 + i;
        #pragma unroll
        for (int j = 0; j < 4; ++j) {
            int n = n0 + tx * 4 + j;
            if (n < N) {
                float v = acc[i][j];
                if (bias1) v += bias1[n];
                if (bias2) v += bias2[n];
                if (ACT == 1) v = tanhf(v);
                if (ACT == 2) v = sigmoidf_(v) * xmul[(size_t)m * N + n];
                if (ACT == 3) {
                    // xf_t[t][n][b]: t = m%1024, b = m/1024
                    C[((size_t)(m & 1023) << 13) + ((size_t)n << 4) + (m >> 10)] = v;
                } else {
                    C[(size_t)m * N + n] = v;
                }
            }
        }
    }
}

// ---------------- persistent fused LSTM (w_ih GEMM fused into recurrence) ----------------
// 256 WGs x 512 thr. Sync design (round-3, verified): no fences; h via sc0sc1 coherence-point
// loads/stores; relaxed atomics. Round-4 change: two-level barrier (8 groups x 16 WGs ->
// master, per-lstm) to cut single-line atomic RMW serialization 256 -> 16+8; xf prefetched
// into registers one step ahead (L2 latency off the critical path).
__global__ __launch_bounds__(512, 2)
void lstm_fused(const float* __restrict__ xf_t,
                const float* __restrict__ k_wih, const float* __restrict__ k_whh,
                const float* __restrict__ k_bih, const float* __restrict__ k_bhh,
                const float* __restrict__ q_wih, const float* __restrict__ q_whh,
                const float* __restrict__ q_bih, const float* __restrict__ q_bhh,
                float* __restrict__ k_out, float* __restrict__ q_out,
                float* __restrict__ hbuf, int* __restrict__ sub, int* __restrict__ mst)
{
    const int wg = blockIdx.x, tid = threadIdx.x;
    const int lstm = wg >> 7;
    const int u0 = (wg & 127) * 4;
    const int grp = (wg & 127) >> 4;             // 8 groups of 16 WGs per lstm
    const float* wih = lstm ? q_wih : k_wih;
    const float* whh = lstm ? q_whh : k_whh;
    const float* bih = lstm ? q_bih : k_bih;
    const float* bhh = lstm ? q_bhh : k_bhh;
    float* out = lstm ? q_out : k_out;
    float* hb = hbuf + lstm * 16384;
    int* subc = sub + ((lstm * 8 + grp) << 10);  // [t]
    int* mstc = mst + (lstm << 10);              // [t]

    const int wv = tid >> 6, lane = tid & 63;
    const int cg = lane & 3, bg = (lane >> 2) & 3, ks = lane >> 4;

    float4 wreg[4][8];          // [gate][k-quad]
    {
        const float* Wsrc = (wv < 4) ? wih : whh;
        const int kbase = (wv & 3) * 128 + ks * 32;
        #pragma unroll
        for (int j = 0; j < 4; ++j) {
            const float4* wp = (const float4*)(Wsrc + ((size_t)(j * 512 + u0 + cg) << 9) + kbase);
            #pragma unroll
            for (int i = 0; i < 8; ++i) wreg[j][i] = wp[i];
        }
    }

    __shared__ __align__(16) float vec[16384];   // concat(xf_t, h) as [k][batch], 64 KB
    __shared__ float part[16][16][33];           // [col][batch][wv*4+ks]
    __shared__ float gsum[256];                  // [col][batch] reduced

    const int cu = tid & 3, cb = tid >> 2;       // gate-thread mapping (tid<64)
    float bI = 0.f, bF = 0.f, bG = 0.f, bO = 0.f, cst = 0.f;
    if (tid < 64) {
        bI = bih[0 * 512 + u0 + cu] + bhh[0 * 512 + u0 + cu];
        bF = bih[1 * 512 + u0 + cu] + bhh[1 * 512 + u0 + cu];
        bG = bih[2 * 512 + u0 + cu] + bhh[2 * 512 + u0 + cu];
        bO = bih[3 * 512 + u0 + cu] + bhh[3 * 512 + u0 + cu];
    }

    // prefetch xf for t=0
    float4 xfr0, xfr1, xfr2, xfr3;
    {
        const float4* xs = (const float4*)xf_t;
        xfr0 = xs[0 * 512 + tid]; xfr1 = xs[1 * 512 + tid];
        xfr2 = xs[2 * 512 + tid]; xfr3 = xs[3 * 512 + tid];
    }

    for (int t = 0; t < T_; ++t) {
        const int rb = t & 1;
        {
            float4* vd = (float4*)vec;
            vd[0 * 512 + tid] = xfr0;
            vd[1 * 512 + tid] = xfr1;
            vd[2 * 512 + tid] = xfr2;
            vd[3 * 512 + tid] = xfr3;
            // h: coherence-point loads (bypass stale L1/L2), 4 in flight then one wait
            const float4* hp = (const float4*)(hb + rb * 8192);
            const float4* p0 = hp + 0 * 512 + tid;
            const float4* p1 = hp + 1 * 512 + tid;
            const float4* p2 = hp + 2 * 512 + tid;
            const float4* p3 = hp + 3 * 512 + tid;
            float4 h0, h1, h2, h3;
            asm volatile(
                "global_load_dwordx4 %0, %4, off sc0 sc1\n\t"
                "global_load_dwordx4 %1, %5, off sc0 sc1\n\t"
                "global_load_dwordx4 %2, %6, off sc0 sc1\n\t"
                "global_load_dwordx4 %3, %7, off sc0 sc1\n\t"
                "s_waitcnt vmcnt(0)"
                : "=&v"(h0), "=&v"(h1), "=&v"(h2), "=&v"(h3)
                : "v"(p0), "v"(p1), "v"(p2), "v"(p3)
                : "memory");
            vd[2048 + 0 * 512 + tid] = h0;
            vd[2048 + 1 * 512 + tid] = h1;
            vd[2048 + 2 * 512 + tid] = h2;
            vd[2048 + 3 * 512 + tid] = h3;
            // issue next-step xf prefetch; latency hides under compute + barrier
            if (t + 1 < T_) {
                const float4* xs2 = (const float4*)(xf_t + ((size_t)(t + 1) << 13));
                xfr0 = xs2[0 * 512 + tid]; xfr1 = xs2[1 * 512 + tid];
                xfr2 = xs2[2 * 512 + tid]; xfr3 = xs2[3 * 512 + tid];
            }
        }
        __syncthreads();

        float4 a0 = {0,0,0,0}, a1 = {0,0,0,0}, a2 = {0,0,0,0}, a3 = {0,0,0,0};
        {
            const float4* vb = ((const float4*)vec) + (((size_t)wv * 128 + ks * 32) << 2) + bg;
            #pragma unroll
            for (int i = 0; i < 8; ++i) {
                float4 v0 = vb[(i * 4 + 0) * 4];
                float4 v1 = vb[(i * 4 + 1) * 4];
                float4 v2 = vb[(i * 4 + 2) * 4];
                float4 v3 = vb[(i * 4 + 3) * 4];
                float4 w;
                #define FMA4_(A) \
                    A.x += w.x * v0.x + w.y * v1.x + w.z * v2.x + w.w * v3.x; \
                    A.y += w.x * v0.y + w.y * v1.y + w.z * v2.y + w.w * v3.y; \
                    A.z += w.x * v0.z + w.y * v1.z + w.z * v2.z + w.w * v3.z; \
                    A.w += w.x * v0.w + w.y * v1.w + w.z * v2.w + w.w * v3.w;
                w = wreg[0][i]; FMA4_(a0)
                w = wreg[1][i]; FMA4_(a1)
                w = wreg[2][i]; FMA4_(a2)
                w = wreg[3][i]; FMA4_(a3)
                #undef FMA4_
            }
        }
        {
            const int s = wv * 4 + ks, c0 = cg * 4, bq = bg * 4;
            part[c0 + 0][bq + 0][s] = a0.x; part[c0 + 0][bq + 1][s] = a0.y;
            part[c0 + 0][bq + 2][s] = a0.z; part[c0 + 0][bq + 3][s] = a0.w;
            part[c0 + 1][bq + 0][s] = a1.x; part[c0 + 1][bq + 1][s] = a1.y;
            part[c0 + 1][bq + 2][s] = a1.z; part[c0 + 1][bq + 3][s] = a1.w;
            part[c0 + 2][bq + 0][s] = a2.x; part[c0 + 2][bq + 1][s] = a2.y;
            part[c0 + 2][bq + 2][s] = a2.z; part[c0 + 2][bq + 3][s] = a2.w;
            part[c0 + 3][bq + 0][s] = a3.x; part[c0 + 3][bq + 1][s] = a3.y;
            part[c0 + 3][bq + 2][s] = a3.z; part[c0 + 3][bq + 3][s] = a3.w;
        }
        __syncthreads();

        if (tid < 256) {            // 2-phase reduce: 4 waves sum 32 partials each
            const int c = tid >> 4, b = tid & 15;
            float s = 0.f;
            #pragma unroll
            for (int ss = 0; ss < 32; ++ss) s += part[c][b][ss];
            gsum[c * 16 + b] = s;
        }
        __syncthreads();

        if (tid < 64) {
            float gI = bI + gsum[(cu * 4 + 0) * 16 + cb];
            float gF = bF + gsum[(cu * 4 + 1) * 16 + cb];
            float gG = bG + gsum[(cu * 4 + 2) * 16 + cb];
            float gO = bO + gsum[(cu * 4 + 3) * 16 + cb];
            float ig = sigmoidf_(gI), fg = sigmoidf_(gF), gg = tanhf(gG), og = sigmoidf_(gO);
            cst = fg * cst + ig * gg;
            float h = og * tanhf(cst);
            // coherence-point store — globally visible once vmcnt retires
            __hip_atomic_store(&hb[(rb ^ 1) * 8192 + ((u0 + cu) << 4) + cb], h,
                               __ATOMIC_RELAXED, __HIP_MEMORY_SCOPE_SYSTEM);
            out[((size_t)(cb * T_ + t) << 9) + (u0 + cu)] = h;
        }
        asm volatile("s_waitcnt vmcnt(0)" ::: "memory");  // h stores acked at coherence point
        __syncthreads();
        if (tid == 0) {
            // two-level arrival: 16 RMWs on 8 parallel lines, then 8 RMWs on master line.
            // sub-add issued after this WG's vmcnt(0) => master==8 implies all 128 WGs'
            // h stores are at the coherence point.
            int old = __hip_atomic_fetch_add(&subc[t], 1, __ATOMIC_RELAXED, __HIP_MEMORY_SCOPE_AGENT);
            if (old == 15)
                __hip_atomic_fetch_add(&mstc[t], 1, __ATOMIC_RELAXED, __HIP_MEMORY_SCOPE_AGENT);
            while (__hip_atomic_load(&mstc[t], __ATOMIC_RELAXED, __HIP_MEMORY_SCOPE_SYSTEM) < 8)
                __builtin_amdgcn_s_sleep(2);
        }
        __syncthreads();
    }
}

// ---------------- attention pass 1: banded causal exp-scores -> normalized rows ----------------
__global__ __launch_bounds__(256)
void attn_scores(const float* __restrict__ qs, const float* __restrict__ kk,
                 float* __restrict__ attn_out)
{
    int t = blockIdx.x, b = blockIdx.y, tid = threadIdx.x;
    int jlo = t - ALEN; if (jlo < 0) jlo = 0;
    int cnt = t - jlo + 1;                       // <= 129
    __shared__ __align__(16) float qrow[512];
    __shared__ float sc[132];
    __shared__ float ssum;
    const float* qsr = qs + ((size_t)(b * T_ + t) << 9);
    qrow[tid] = qsr[tid];
    qrow[tid + 256] = qsr[tid + 256];
    __syncthreads();
    if (tid < cnt) {
        const float4* krow = (const float4*)(kk + ((size_t)(b * T_ + jlo + tid) << 9));
        const float4* q4 = (const float4*)qrow;
        float acc = 0.f;
        #pragma unroll 4
        for (int i = 0; i < 128; ++i) {
            float4 kv = krow[i]; float4 qv = q4[i];
            acc += kv.x * qv.x + kv.y * qv.y + kv.z * qv.z + kv.w * qv.w;
        }
        sc[tid] = expf(acc);                     // no max-subtraction (faithful to reference)
    }
    __syncthreads();
    if (tid < 64) {
        float s = 0.f;
        for (int j = tid; j < cnt; j += 64) s += sc[j];
        #pragma unroll
        for (int off = 32; off > 0; off >>= 1) s += __shfl_down(s, off);
        if (tid == 0) ssum = s + 1e-10f;
    }
    __syncthreads();
    float inv = 1.0f / ssum;
    // full row incl. zeros outside band (d_out is poisoned pre-launch)
    float4* arow = (float4*)(attn_out + ((size_t)(b * T_ + t) << 10));
    int j0 = tid * 4;
    float4 v;
    v.x = (j0 + 0 >= jlo && j0 + 0 <= t) ? sc[j0 + 0 - jlo] * inv : 0.f;
    v.y = (j0 + 1 >= jlo && j0 + 1 <= t) ? sc[j0 + 1 - jlo] * inv : 0.f;
    v.z = (j0 + 2 >= jlo && j0 + 2 <= t) ? sc[j0 + 2 - jlo] * inv : 0.f;
    v.w = (j0 + 3 >= jlo && j0 + 3 <= t) ? sc[j0 + 3 - jlo] * inv : 0.f;
    arow[tid] = v;
}

// ---------------- attention pass 2: c = attn(normalized rows) @ k ----------------
__global__ __launch_bounds__(256)
void attn_ctx(const float* __restrict__ attn, const float* __restrict__ kk,
              float* __restrict__ c_out)
{
    int t = blockIdx.x, b = blockIdx.y, tid = threadIdx.x;
    int jlo = t - ALEN; if (jlo < 0) jlo = 0;
    int cnt = t - jlo + 1;
    __shared__ float sc[132];
    if (tid < cnt) sc[tid] = attn[((size_t)(b * T_ + t) << 10) + jlo + tid];
    __syncthreads();
    #pragma unroll
    for (int hh = 0; hh < 2; ++hh) {
        int h = tid + hh * 256;
        const float* kcol = kk + ((size_t)(b * T_ + jlo) << 9) + h;
        float acc = 0.f;
        #pragma unroll 4
        for (int jj = 0; jj < cnt; ++jj) acc += sc[jj] * kcol[(size_t)jj << 9];
        c_out[((size_t)(b * T_ + t) << 9) + h] = acc;
    }
}

extern "C" void kernel_launch(void* const* d_in, const int* in_sizes, int n_in,
                              void* d_out_v, int out_size, void* d_ws, size_t ws_size,
                              hipStream_t stream)
{
    const float* x       = (const float*)d_in[0];
    const float* feat_w  = (const float*)d_in[1];
    const float* feat_b  = (const float*)d_in[2];
    const float* k_w_ih  = (const float*)d_in[3];
    const float* k_w_hh  = (const float*)d_in[4];
    const float* k_b_ih  = (const float*)d_in[5];
    const float* k_b_hh  = (const float*)d_in[6];
    const float* q_w_ih  = (const float*)d_in[7];
    const float* q_w_hh  = (const float*)d_in[8];
    const float* q_b_ih  = (const float*)d_in[9];
    const float* q_b_hh  = (const float*)d_in[10];
    const float* score_w = (const float*)d_in[11];
    const float* enh_w   = (const float*)d_in[12];
    const float* enh_b   = (const float*)d_in[13];
    const float* mask_w  = (const float*)d_in[14];
    const float* mask_b  = (const float*)d_in[15];
    float* out = (float*)d_out_v;
    float* ws  = (float*)d_ws;

    if (ws_size < WS_NEED * sizeof(float)) return;  // clean fail if ws too small

    float* bufA = ws + OFF_A;   // xf_t -> qs -> c
    float* bufB = ws + OFF_B;   // k -> enh
    float* bufC = ws + OFF_C;   // q
    float* hbuf = ws + OFF_HB;
    int*   sub  = (int*)(ws + OFF_SUB);
    int*   mst  = (int*)(ws + OFF_MST);

    // zero h double-buffers + all barrier counters (contiguous region)
    hipMemsetAsync(hbuf, 0, (32768 + 16384 + 2048) * sizeof(float), stream);

    dim3 blk(256);
    // xf_t[t][n][b] = x @ feat_w^T + feat_b   (transposed store for LSTM staging)
    gemm_kernel<3><<<dim3(8, 256), blk, 0, stream>>>(x, nullptr, F_, feat_w, feat_b, nullptr, nullptr, bufA, BT, H_, F_);
    // fused recurrence, both LSTMs (w_ih + w_hh + biases inside)
    lstm_fused<<<dim3(LSTM_NWG), dim3(512), 0, stream>>>(bufA,
        k_w_ih, k_w_hh, k_b_ih, k_b_hh, q_w_ih, q_w_hh, q_b_ih, q_b_hh,
        bufB, bufC, hbuf, sub, mst);
    // qs = q @ score_w^T  (overwrites xf_t, dead)
    gemm_kernel<0><<<dim3(8, 256), blk, 0, stream>>>(bufC, nullptr, H_, score_w, nullptr, nullptr, nullptr, bufA, BT, H_, H_);
    // attn rows -> d_out tail
    attn_scores<<<dim3(T_, B_), blk, 0, stream>>>(bufA, bufB, out + (size_t)BT * F_);
    // c = attn @ k  (overwrites qs, dead)
    attn_ctx<<<dim3(T_, B_), blk, 0, stream>>>(out + (size_t)BT * F_, bufB, bufA);
    // enh = tanh(concat(c, q) @ enh_w^T + enh_b)  (overwrites k, dead)
    gemm_kernel<1><<<dim3(8, 256), blk, 0, stream>>>(bufA, bufC, H_, enh_w, enh_b, nullptr, nullptr, bufB, BT, H_, 2 * H_);
    // out = sigmoid(enh @ mask_w^T + mask_b) * x
    gemm_kernel<2><<<dim3(5, 256), blk, 0, stream>>>(bufB, nullptr, H_, mask_w, mask_b, nullptr, x, out, BT, F_, H_);
}

// Round 6
// 7967.903 us; speedup vs baseline: 10.6765x; 1.0095x over previous
//
#include <hip/hip_runtime.h>
#include <hip/hip_bf16.h>
#include <math.h>

#define B_ 16
#define T_ 1024
#define F_ 257
#define H_ 512
#define BT (B_*T_)
#define ALEN 128
#define LSTM_NWG 256

// ---- workspace layout (float offsets) ---- total ~96.2 MiB
// A: xf_t -> qs -> c ; B: k -> enh ; C: q
static const size_t OFF_A    = 0;
static const size_t OFF_B    = OFF_A + (size_t)BT*H_;
static const size_t OFF_C    = OFF_B + (size_t)BT*H_;
static const size_t OFF_HB   = OFF_C + (size_t)BT*H_;   // 2 lstm * 2 buf * 8192 floats
static const size_t OFF_SUB  = OFF_HB + 32768;          // 2*8*1024 ints (group counters)
static const size_t OFF_MST  = OFF_SUB + 16384;         // 2*1024 ints (master counters)
static const size_t WS_NEED  = OFF_MST + 2048;          // floats

__device__ __forceinline__ float sigmoidf_(float v) { return 1.0f / (1.0f + expf(-v)); }

// ---------------- generic f32 GEMM: C = act(A @ W^T + bias1 (+bias2)) ----------------
// ACT: 0 none, 1 tanh, 2 sigmoid * xmul[m*N+n], 3 none + transposed store C[t][n][b]
template<int ACT>
__global__ __launch_bounds__(256)
void gemm_kernel(const float* __restrict__ A1, const float* __restrict__ A2, int K1,
                 const float* __restrict__ W, const float* __restrict__ bias1,
                 const float* __restrict__ bias2, const float* __restrict__ xmul,
                 float* __restrict__ C, int M, int N, int K)
{
    __shared__ __align__(16) float As[16][68];
    __shared__ __align__(16) float Ws[16][68];
    int tid = threadIdx.x;
    int tx = tid & 15, ty = tid >> 4;
    int m0 = blockIdx.y * 64, n0 = blockIdx.x * 64;
    int lrow = tid >> 2, lk = (tid & 3) * 4;
    float acc[4][4] = {};
    int ntiles = (K + 15) >> 4;
    int ldA2 = K - K1;
    for (int kt = 0; kt < ntiles; ++kt) {
        int k0 = kt << 4;
        #pragma unroll
        for (int j = 0; j < 4; ++j) {
            int k = k0 + lk + j;
            float av = 0.0f, wv = 0.0f;
            if (k < K) {
                int m = m0 + lrow;
                av = (k < K1) ? A1[(size_t)m * K1 + k] : A2[(size_t)m * ldA2 + (k - K1)];
                int n = n0 + lrow;
                if (n < N) wv = W[(size_t)n * K + k];
            }
            As[lk + j][lrow] = av;
            Ws[lk + j][lrow] = wv;
        }
        __syncthreads();
        #pragma unroll
        for (int kk = 0; kk < 16; ++kk) {
            float4 a = *(const float4*)&As[kk][ty * 4];
            float4 w = *(const float4*)&Ws[kk][tx * 4];
            acc[0][0] += a.x * w.x; acc[0][1] += a.x * w.y; acc[0][2] += a.x * w.z; acc[0][3] += a.x * w.w;
            acc[1][0] += a.y * w.x; acc[1][1] += a.y * w.y; acc[1][2] += a.y * w.z; acc[1][3] += a.y * w.w;
            acc[2][0] += a.z * w.x; acc[2][1] += a.z * w.y; acc[2][2] += a.z * w.z; acc[2][3] += a.z * w.w;
            acc[3][0] += a.w * w.x; acc[3][1] += a.w * w.y; acc[3][2] += a.w * w.z; acc[3][3] += a.w * w.w;
        }
        __syncthreads();
    }
    #pragma unroll
    for (int i = 0; i < 4; ++i) {
        int m = m0 + ty * 4 + i;
        #pragma unroll
        for (int j = 0; j < 4; ++j) {
            int n = n0 + tx * 4 + j;
            if (n < N) {
                float v = acc[i][j];
                if (bias1) v += bias1[n];
                if (bias2) v += bias2[n];
                if (ACT == 1) v = tanhf(v);
                if (ACT == 2) v = sigmoidf_(v) * xmul[(size_t)m * N + n];
                if (ACT == 3) {
                    // xf_t[t][n][b]: t = m%1024, b = m/1024
                    C[((size_t)(m & 1023) << 13) + ((size_t)n << 4) + (m >> 10)] = v;
                } else {
                    C[(size_t)m * N + n] = v;
                }
            }
        }
    }
}

// ---------------- persistent fused LSTM ----------------
// Round-6 restructure:
//  * per-wave self-owned vec slices (stage->lgkmcnt->compute, NO barrier in between)
//  * barrier wait lives in hh-waves only (wave4 polls global mst, releases 5-7 via LDS flag);
//    ih-waves compute the w_ih half + stage/prefetch xf UNDER the wait
//  * vec block-padded (+2 float4 per 32-k block) -> 2-way (free) LDS banking
//  * 32 NAMED float4 weight regs -> forced VGPR residency (r5: VGPR=104 proved remat)
//  * 2 syncthreads/step (post-part, post-reduce); end-of-step barrier removed (ordering
//    proof: part overwrite at t+1 is gated by poll(t) <- own arrival <- finalize <- mid-sync
//    <- reduce complete; double-buffer hb safe because arrival(t) is program-after reads(t))
__global__ __launch_bounds__(512, 2)
void lstm_fused(const float* __restrict__ xf_t,
                const float* __restrict__ k_wih, const float* __restrict__ k_whh,
                const float* __restrict__ k_bih, const float* __restrict__ k_bhh,
                const float* __restrict__ q_wih, const float* __restrict__ q_whh,
                const float* __restrict__ q_bih, const float* __restrict__ q_bhh,
                float* __restrict__ k_out, float* __restrict__ q_out,
                float* __restrict__ hbuf, int* __restrict__ sub, int* __restrict__ mst)
{
    const int wg = blockIdx.x, tid = threadIdx.x;
    const int lstm = wg >> 7;
    const int u0 = (wg & 127) * 4;
    const int grp = (wg & 127) >> 4;             // 8 groups of 16 WGs per lstm
    const float* wih = lstm ? q_wih : k_wih;
    const float* whh = lstm ? q_whh : k_whh;
    const float* bih = lstm ? q_bih : k_bih;
    const float* bhh = lstm ? q_bhh : k_bhh;
    float* out = lstm ? q_out : k_out;
    float* hb = hbuf + lstm * 16384;
    int* subc = sub + ((lstm * 8 + grp) << 10);  // [t]
    int* mstc = mst + (lstm << 10);              // [t]

    const int wv = tid >> 6, lane = tid & 63;
    const int cg = lane & 3, bg = (lane >> 2) & 3, ks = lane >> 4;

    // ---- 32 named weight float4s (forced register residency) ----
    float4 w00,w01,w02,w03,w04,w05,w06,w07;
    float4 w10,w11,w12,w13,w14,w15,w16,w17;
    float4 w20,w21,w22,w23,w24,w25,w26,w27;
    float4 w30,w31,w32,w33,w34,w35,w36,w37;
    {
        const float* Wsrc = (wv < 4) ? wih : whh;
        const int kb = (wv & 3) * 128 + ks * 32;
        const float4* p;
        p = (const float4*)(Wsrc + ((size_t)(0 * 512 + u0 + cg) << 9) + kb);
        w00=p[0];w01=p[1];w02=p[2];w03=p[3];w04=p[4];w05=p[5];w06=p[6];w07=p[7];
        p = (const float4*)(Wsrc + ((size_t)(1 * 512 + u0 + cg) << 9) + kb);
        w10=p[0];w11=p[1];w12=p[2];w13=p[3];w14=p[4];w15=p[5];w16=p[6];w17=p[7];
        p = (const float4*)(Wsrc + ((size_t)(2 * 512 + u0 + cg) << 9) + kb);
        w20=p[0];w21=p[1];w22=p[2];w23=p[3];w24=p[4];w25=p[5];w26=p[6];w27=p[7];
        p = (const float4*)(Wsrc + ((size_t)(3 * 512 + u0 + cg) << 9) + kb);
        w30=p[0];w31=p[1];w32=p[2];w33=p[3];w34=p[4];w35=p[5];w36=p[6];w37=p[7];
    }

    // vec: [xf 16 blocks | h 16 blocks], block = 32 k x 16 b = 128 float4, +2 pad -> 130
    __shared__ __align__(16) float4 vec4[4160];   // 66560 B
    __shared__ float part[16][16][33];            // [col][batch][s]
    __shared__ float gsum[256];                   // [col][batch]
    __shared__ int ready;                         // LDS release flag (wave4 -> waves 5-7)

    const int cu = tid & 3, cb = tid >> 2;        // finalize mapping (tid<64)
    float bI = 0.f, bF = 0.f, bG = 0.f, bO = 0.f, cst = 0.f;
    if (tid < 64) {
        bI = bih[0 * 512 + u0 + cu] + bhh[0 * 512 + u0 + cu];
        bF = bih[1 * 512 + u0 + cu] + bhh[1 * 512 + u0 + cu];
        bG = bih[2 * 512 + u0 + cu] + bhh[2 * 512 + u0 + cu];
        bO = bih[3 * 512 + u0 + cu] + bhh[3 * 512 + u0 + cu];
    }
    if (tid == 0) ready = 0;

    // xf prefetch for t=0 (ih waves own their slice: 8 float4/lane)
    float4 xf0{},xf1{},xf2{},xf3{},xf4{},xf5{},xf6{},xf7{};
    if (wv < 4) {
        const float4* xs = (const float4*)xf_t + (wv << 9) + lane;
        xf0=xs[0];  xf1=xs[64];  xf2=xs[128]; xf3=xs[192];
        xf4=xs[256];xf5=xs[320]; xf6=xs[384]; xf7=xs[448];
    }
    __syncthreads();   // ready init visible

    for (int t = 0; t < T_; ++t) {
        const int rb = t & 1;
        float4 a0{},a1{},a2{},a3{};
        const float4* vb;
        if (wv < 4) {
            // ---- ih wave: stage own xf slice, prefetch next, compute (overlaps hh wait) ----
            const int xb = wv * 520;  // wv*4 blocks * 130
            vec4[xb +   0 + lane] = xf0;
            vec4[xb +  64 + lane] = xf1;
            vec4[xb + 130 + lane] = xf2;
            vec4[xb + 194 + lane] = xf3;
            vec4[xb + 260 + lane] = xf4;
            vec4[xb + 324 + lane] = xf5;
            vec4[xb + 390 + lane] = xf6;
            vec4[xb + 454 + lane] = xf7;
            if (t + 1 < T_) {
                const float4* xs = (const float4*)(xf_t + ((size_t)(t + 1) << 13)) + (wv << 9) + lane;
                xf0=xs[0];  xf1=xs[64];  xf2=xs[128]; xf3=xs[192];
                xf4=xs[256];xf5=xs[320]; xf6=xs[384]; xf7=xs[448];
            }
            asm volatile("s_waitcnt lgkmcnt(0)" ::: "memory");  // cross-lane LDS visibility
            vb = vec4 + xb + ks * 130 + bg;
        } else {
            // ---- hh wave: wait for h_{t-1}, stage own h slice, compute ----
            if (t > 0) {
                if (wv == 4) {
                    while (__hip_atomic_load(&mstc[t - 1], __ATOMIC_RELAXED, __HIP_MEMORY_SCOPE_SYSTEM) < 8)
                        __builtin_amdgcn_s_sleep(2);
                    if (lane == 0)
                        __hip_atomic_store(&ready, t, __ATOMIC_RELAXED, __HIP_MEMORY_SCOPE_WORKGROUP);
                } else {
                    while (__hip_atomic_load(&ready, __ATOMIC_RELAXED, __HIP_MEMORY_SCOPE_WORKGROUP) < t)
                        __builtin_amdgcn_s_sleep(1);
                }
            }
            const float4* hp  = (const float4*)(hb + rb * 8192) + ((wv - 4) << 9) + lane;
            const float4* hp2 = hp + 256;
            float4 h0,h1,h2,h3,h4,h5,h6,h7;
            asm volatile(
                "global_load_dwordx4 %0, %8, off sc0 sc1\n\t"
                "global_load_dwordx4 %1, %8, off offset:1024 sc0 sc1\n\t"
                "global_load_dwordx4 %2, %8, off offset:2048 sc0 sc1\n\t"
                "global_load_dwordx4 %3, %8, off offset:3072 sc0 sc1\n\t"
                "global_load_dwordx4 %4, %9, off sc0 sc1\n\t"
                "global_load_dwordx4 %5, %9, off offset:1024 sc0 sc1\n\t"
                "global_load_dwordx4 %6, %9, off offset:2048 sc0 sc1\n\t"
                "global_load_dwordx4 %7, %9, off offset:3072 sc0 sc1\n\t"
                "s_waitcnt vmcnt(0)"
                : "=&v"(h0),"=&v"(h1),"=&v"(h2),"=&v"(h3),
                  "=&v"(h4),"=&v"(h5),"=&v"(h6),"=&v"(h7)
                : "v"(hp), "v"(hp2)
                : "memory");
            const int hbv = 2080 + (wv - 4) * 520;
            vec4[hbv +   0 + lane] = h0;
            vec4[hbv +  64 + lane] = h1;
            vec4[hbv + 130 + lane] = h2;
            vec4[hbv + 194 + lane] = h3;
            vec4[hbv + 260 + lane] = h4;
            vec4[hbv + 324 + lane] = h5;
            vec4[hbv + 390 + lane] = h6;
            vec4[hbv + 454 + lane] = h7;
            asm volatile("s_waitcnt lgkmcnt(0)" ::: "memory");
            vb = vec4 + hbv + ks * 130 + bg;
        }

        #define FMA4_(A, W) \
            A.x += W.x*v0.x + W.y*v1.x + W.z*v2.x + W.w*v3.x; \
            A.y += W.x*v0.y + W.y*v1.y + W.z*v2.y + W.w*v3.y; \
            A.z += W.x*v0.z + W.y*v1.z + W.z*v2.z + W.w*v3.z; \
            A.w += W.x*v0.w + W.y*v1.w + W.z*v2.w + W.w*v3.w;
        #define FSTEP(i, WA, WB, WC, WD) { \
            float4 v0 = vb[(i)*16], v1 = vb[(i)*16+4], v2 = vb[(i)*16+8], v3 = vb[(i)*16+12]; \
            FMA4_(a0, WA) FMA4_(a1, WB) FMA4_(a2, WC) FMA4_(a3, WD) }
        FSTEP(0, w00,w10,w20,w30)
        FSTEP(1, w01,w11,w21,w31)
        FSTEP(2, w02,w12,w22,w32)
        FSTEP(3, w03,w13,w23,w33)
        FSTEP(4, w04,w14,w24,w34)
        FSTEP(5, w05,w15,w25,w35)
        FSTEP(6, w06,w16,w26,w36)
        FSTEP(7, w07,w17,w27,w37)
        #undef FSTEP
        #undef FMA4_

        {
            const int s = wv * 4 + ks, c0 = cg * 4, bq = bg * 4;
            part[c0 + 0][bq + 0][s] = a0.x; part[c0 + 0][bq + 1][s] = a0.y;
            part[c0 + 0][bq + 2][s] = a0.z; part[c0 + 0][bq + 3][s] = a0.w;
            part[c0 + 1][bq + 0][s] = a1.x; part[c0 + 1][bq + 1][s] = a1.y;
            part[c0 + 1][bq + 2][s] = a1.z; part[c0 + 1][bq + 3][s] = a1.w;
            part[c0 + 2][bq + 0][s] = a2.x; part[c0 + 2][bq + 1][s] = a2.y;
            part[c0 + 2][bq + 2][s] = a2.z; part[c0 + 2][bq + 3][s] = a2.w;
            part[c0 + 3][bq + 0][s] = a3.x; part[c0 + 3][bq + 1][s] = a3.y;
            part[c0 + 3][bq + 2][s] = a3.z; part[c0 + 3][bq + 3][s] = a3.w;
        }
        __syncthreads();                       // part complete

        if (tid < 256) {                       // waves 0-3 reduce
            const int c = tid >> 4, b = tid & 15;
            float s2 = 0.f;
            #pragma unroll
            for (int ss = 0; ss < 32; ++ss) s2 += part[c][b][ss];
            gsum[c * 16 + b] = s2;
        }
        __syncthreads();                       // gsum ready (also: reduce reads done)

        if (tid < 64) {                        // wave 0 finalize + h store
            float gI = bI + gsum[(cu * 4 + 0) * 16 + cb];
            float gF = bF + gsum[(cu * 4 + 1) * 16 + cb];
            float gG = bG + gsum[(cu * 4 + 2) * 16 + cb];
            float gO = bO + gsum[(cu * 4 + 3) * 16 + cb];
            float ig = sigmoidf_(gI), fg = sigmoidf_(gF), gg = tanhf(gG), og = sigmoidf_(gO);
            cst = fg * cst + ig * gg;
            float h = og * tanhf(cst);
            __hip_atomic_store(&hb[((rb ^ 1) << 13) + ((u0 + cu) << 4) + cb], h,
                               __ATOMIC_RELAXED, __HIP_MEMORY_SCOPE_SYSTEM);
            out[((size_t)(cb * T_ + t) << 9) + (u0 + cu)] = h;
            asm volatile("s_waitcnt vmcnt(0)" ::: "memory");  // h at coherence point (wave 0)
        }
        if (tid == 0) {
            // arrival after wave-0 vmcnt(0): master==8 => all 128 WGs' h visible
            int old = __hip_atomic_fetch_add(&subc[t], 1, __ATOMIC_RELAXED, __HIP_MEMORY_SCOPE_AGENT);
            if (old == 15)
                __hip_atomic_fetch_add(&mstc[t], 1, __ATOMIC_RELAXED, __HIP_MEMORY_SCOPE_AGENT);
        }
        // no end-of-step barrier: next-iter hazards gated by poll/arrival chain (see header)
    }
}

// ---------------- attention pass 1: banded causal exp-scores -> normalized rows ----------------
__global__ __launch_bounds__(256)
void attn_scores(const float* __restrict__ qs, const float* __restrict__ kk,
                 float* __restrict__ attn_out)
{
    int t = blockIdx.x, b = blockIdx.y, tid = threadIdx.x;
    int jlo = t - ALEN; if (jlo < 0) jlo = 0;
    int cnt = t - jlo + 1;                       // <= 129
    __shared__ __align__(16) float qrow[512];
    __shared__ float sc[132];
    __shared__ float ssum;
    const float* qsr = qs + ((size_t)(b * T_ + t) << 9);
    qrow[tid] = qsr[tid];
    qrow[tid + 256] = qsr[tid + 256];
    __syncthreads();
    if (tid < cnt) {
        const float4* krow = (const float4*)(kk + ((size_t)(b * T_ + jlo + tid) << 9));
        const float4* q4 = (const float4*)qrow;
        float acc = 0.f;
        #pragma unroll 4
        for (int i = 0; i < 128; ++i) {
            float4 kv = krow[i]; float4 qv = q4[i];
            acc += kv.x * qv.x + kv.y * qv.y + kv.z * qv.z + kv.w * qv.w;
        }
        sc[tid] = expf(acc);                     // no max-subtraction (faithful to reference)
    }
    __syncthreads();
    if (tid < 64) {
        float s = 0.f;
        for (int j = tid; j < cnt; j += 64) s += sc[j];
        #pragma unroll
        for (int off = 32; off > 0; off >>= 1) s += __shfl_down(s, off);
        if (tid == 0) ssum = s + 1e-10f;
    }
    __syncthreads();
    float inv = 1.0f / ssum;
    float4* arow = (float4*)(attn_out + ((size_t)(b * T_ + t) << 10));
    int j0 = tid * 4;
    float4 v;
    v.x = (j0 + 0 >= jlo && j0 + 0 <= t) ? sc[j0 + 0 - jlo] * inv : 0.f;
    v.y = (j0 + 1 >= jlo && j0 + 1 <= t) ? sc[j0 + 1 - jlo] * inv : 0.f;
    v.z = (j0 + 2 >= jlo && j0 + 2 <= t) ? sc[j0 + 2 - jlo] * inv : 0.f;
    v.w = (j0 + 3 >= jlo && j0 + 3 <= t) ? sc[j0 + 3 - jlo] * inv : 0.f;
    arow[tid] = v;
}

// ---------------- attention pass 2: c = attn(normalized rows) @ k ----------------
__global__ __launch_bounds__(256)
void attn_ctx(const float* __restrict__ attn, const float* __restrict__ kk,
              float* __restrict__ c_out)
{
    int t = blockIdx.x, b = blockIdx.y, tid = threadIdx.x;
    int jlo = t - ALEN; if (jlo < 0) jlo = 0;
    int cnt = t - jlo + 1;
    __shared__ float sc[132];
    if (tid < cnt) sc[tid] = attn[((size_t)(b * T_ + t) << 10) + jlo + tid];
    __syncthreads();
    #pragma unroll
    for (int hh = 0; hh < 2; ++hh) {
        int h = tid + hh * 256;
        const float* kcol = kk + ((size_t)(b * T_ + jlo) << 9) + h;
        float acc = 0.f;
        #pragma unroll 4
        for (int jj = 0; jj < cnt; ++jj) acc += sc[jj] * kcol[(size_t)jj << 9];
        c_out[((size_t)(b * T_ + t) << 9) + h] = acc;
    }
}

extern "C" void kernel_launch(void* const* d_in, const int* in_sizes, int n_in,
                              void* d_out_v, int out_size, void* d_ws, size_t ws_size,
                              hipStream_t stream)
{
    const float* x       = (const float*)d_in[0];
    const float* feat_w  = (const float*)d_in[1];
    const float* feat_b  = (const float*)d_in[2];
    const float* k_w_ih  = (const float*)d_in[3];
    const float* k_w_hh  = (const float*)d_in[4];
    const float* k_b_ih  = (const float*)d_in[5];
    const float* k_b_hh  = (const float*)d_in[6];
    const float* q_w_ih  = (const float*)d_in[7];
    const float* q_w_hh  = (const float*)d_in[8];
    const float* q_b_ih  = (const float*)d_in[9];
    const float* q_b_hh  = (const float*)d_in[10];
    const float* score_w = (const float*)d_in[11];
    const float* enh_w   = (const float*)d_in[12];
    const float* enh_b   = (const float*)d_in[13];
    const float* mask_w  = (const float*)d_in[14];
    const float* mask_b  = (const float*)d_in[15];
    float* out = (float*)d_out_v;
    float* ws  = (float*)d_ws;

    if (ws_size < WS_NEED * sizeof(float)) return;  // clean fail if ws too small

    float* bufA = ws + OFF_A;   // xf_t -> qs -> c
    float* bufB = ws + OFF_B;   // k -> enh
    float* bufC = ws + OFF_C;   // q
    float* hbuf = ws + OFF_HB;
    int*   sub  = (int*)(ws + OFF_SUB);
    int*   mst  = (int*)(ws + OFF_MST);

    // zero h double-buffers + all barrier counters (contiguous region)
    hipMemsetAsync(hbuf, 0, (32768 + 16384 + 2048) * sizeof(float), stream);

    dim3 blk(256);
    // xf_t[t][n][b] = x @ feat_w^T + feat_b   (transposed store for LSTM staging)
    gemm_kernel<3><<<dim3(8, 256), blk, 0, stream>>>(x, nullptr, F_, feat_w, feat_b, nullptr, nullptr, bufA, BT, H_, F_);
    // fused recurrence, both LSTMs (w_ih + w_hh + biases inside)
    lstm_fused<<<dim3(LSTM_NWG), dim3(512), 0, stream>>>(bufA,
        k_w_ih, k_w_hh, k_b_ih, k_b_hh, q_w_ih, q_w_hh, q_b_ih, q_b_hh,
        bufB, bufC, hbuf, sub, mst);
    // qs = q @ score_w^T  (overwrites xf_t, dead)
    gemm_kernel<0><<<dim3(8, 256), blk, 0, stream>>>(bufC, nullptr, H_, score_w, nullptr, nullptr, nullptr, bufA, BT, H_, H_);
    // attn rows -> d_out tail
    attn_scores<<<dim3(T_, B_), blk, 0, stream>>>(bufA, bufB, out + (size_t)BT * F_);
    // c = attn @ k  (overwrites qs, dead)
    attn_ctx<<<dim3(T_, B_), blk, 0, stream>>>(out + (size_t)BT * F_, bufB, bufA);
    // enh = tanh(concat(c, q) @ enh_w^T + enh_b)  (overwrites k, dead)
    gemm_kernel<1><<<dim3(8, 256), blk, 0, stream>>>(bufA, bufC, H_, enh_w, enh_b, nullptr, nullptr, bufB, BT, H_, 2 * H_);
    // out = sigmoid(enh @ mask_w^T + mask_b) * x
    gemm_kernel<2><<<dim3(5, 256), blk, 0, stream>>>(bufB, nullptr, H_, mask_w, mask_b, nullptr, x, out, BT, F_, H_);
}

// Round 10
// 7617.332 us; speedup vs baseline: 11.1679x; 1.0460x over previous
//
#include <hip/hip_runtime.h>
#include <hip/hip_bf16.h>
#include <math.h>

#define B_ 16
#define T_ 1024
#define F_ 257
#define H_ 512
#define BT (B_*T_)
#define ALEN 128
#define LSTM_NWG 256

// ---- workspace layout (float offsets) ---- total ~96.2 MiB
// A: xf_t -> qs -> c ; B: k -> enh ; C: q
static const size_t OFF_A    = 0;
static const size_t OFF_B    = OFF_A + (size_t)BT*H_;
static const size_t OFF_C    = OFF_B + (size_t)BT*H_;
static const size_t OFF_HB   = OFF_C + (size_t)BT*H_;   // 2 lstm * 2 buf * 8192 floats
static const size_t OFF_SUB  = OFF_HB + 32768;          // 2*8*1024 ints (group counters)
static const size_t OFF_MST  = OFF_SUB + 16384;         // 2*1024 ints (master counters)
static const size_t WS_NEED  = OFF_MST + 2048;          // floats

__device__ __forceinline__ float sigmoidf_(float v) { return 1.0f / (1.0f + expf(-v)); }

// ---------------- generic f32 GEMM: C = act(A @ W^T + bias1 (+bias2)) ----------------
// ACT: 0 none, 1 tanh, 2 sigmoid * xmul[m*N+n], 3 none + transposed store C[t][n][b]
template<int ACT>
__global__ __launch_bounds__(256)
void gemm_kernel(const float* __restrict__ A1, const float* __restrict__ A2, int K1,
                 const float* __restrict__ W, const float* __restrict__ bias1,
                 const float* __restrict__ bias2, const float* __restrict__ xmul,
                 float* __restrict__ C, int M, int N, int K)
{
    __shared__ __align__(16) float As[16][68];
    __shared__ __align__(16) float Ws[16][68];
    int tid = threadIdx.x;
    int tx = tid & 15, ty = tid >> 4;
    int m0 = blockIdx.y * 64, n0 = blockIdx.x * 64;
    int lrow = tid >> 2, lk = (tid & 3) * 4;
    float acc[4][4] = {};
    int ntiles = (K + 15) >> 4;
    int ldA2 = K - K1;
    for (int kt = 0; kt < ntiles; ++kt) {
        int k0 = kt << 4;
        #pragma unroll
        for (int j = 0; j < 4; ++j) {
            int k = k0 + lk + j;
            float av = 0.0f, wv = 0.0f;
            if (k < K) {
                int m = m0 + lrow;
                av = (k < K1) ? A1[(size_t)m * K1 + k] : A2[(size_t)m * ldA2 + (k - K1)];
                int n = n0 + lrow;
                if (n < N) wv = W[(size_t)n * K + k];
            }
            As[lk + j][lrow] = av;
            Ws[lk + j][lrow] = wv;
        }
        __syncthreads();
        #pragma unroll
        for (int kk = 0; kk < 16; ++kk) {
            float4 a = *(const float4*)&As[kk][ty * 4];
            float4 w = *(const float4*)&Ws[kk][tx * 4];
            acc[0][0] += a.x * w.x; acc[0][1] += a.x * w.y; acc[0][2] += a.x * w.z; acc[0][3] += a.x * w.w;
            acc[1][0] += a.y * w.x; acc[1][1] += a.y * w.y; acc[1][2] += a.y * w.z; acc[1][3] += a.y * w.w;
            acc[2][0] += a.z * w.x; acc[2][1] += a.z * w.y; acc[2][2] += a.z * w.z; acc[2][3] += a.z * w.w;
            acc[3][0] += a.w * w.x; acc[3][1] += a.w * w.y; acc[3][2] += a.w * w.z; acc[3][3] += a.w * w.w;
        }
        __syncthreads();
    }
    #pragma unroll
    for (int i = 0; i < 4; ++i) {
        int m = m0 + ty * 4 + i;
        #pragma unroll
        for (int j = 0; j < 4; ++j) {
            int n = n0 + tx * 4 + j;
            if (n < N) {
                float v = acc[i][j];
                if (bias1) v += bias1[n];
                if (bias2) v += bias2[n];
                if (ACT == 1) v = tanhf(v);
                if (ACT == 2) v = sigmoidf_(v) * xmul[(size_t)m * N + n];
                if (ACT == 3) {
                    // xf_t[t][n][b]: t = m%1024, b = m/1024
                    C[((size_t)(m & 1023) << 13) + ((size_t)n << 4) + (m >> 10)] = v;
                } else {
                    C[(size_t)m * N + n] = v;
                }
            }
        }
    }
}

// ---------------- persistent fused LSTM ----------------
// Round-6 structure (verified): per-wave self-owned vec slices; hh-only barrier wait
// (wave4 polls global, releases 5-7 via LDS flag); padded vec (read banks = 8ks+4bg,
// conflict-free); 2 syncthreads/step; no end-of-step barrier (hazard proof in r6).
// Round-9 change (= r7/r8 intent, compile-fixed twice): LAUNDER the 32 weight float4s
// per scalar component via opaque asm. r7: "+v" on float4 tuples unsupported. r8: macro
// param named `w` clobbered the member token `.w` (w01.w -> w01.w01). Param renamed V.
// Remat of weight loads inside the t-loop becomes impossible (r5 VGPR=104 / r6 VGPR=116
// proved remat; ~64KB/WG/step of L2 weight re-reads sat on the critical path).
__global__ __launch_bounds__(512, 2)
void lstm_fused(const float* __restrict__ xf_t,
                const float* __restrict__ k_wih, const float* __restrict__ k_whh,
                const float* __restrict__ k_bih, const float* __restrict__ k_bhh,
                const float* __restrict__ q_wih, const float* __restrict__ q_whh,
                const float* __restrict__ q_bih, const float* __restrict__ q_bhh,
                float* __restrict__ k_out, float* __restrict__ q_out,
                float* __restrict__ hbuf, int* __restrict__ sub, int* __restrict__ mst)
{
    const int wg = blockIdx.x, tid = threadIdx.x;
    const int lstm = wg >> 7;
    const int u0 = (wg & 127) * 4;
    const int grp = (wg & 127) >> 4;             // 8 groups of 16 WGs per lstm
    const float* wih = lstm ? q_wih : k_wih;
    const float* whh = lstm ? q_whh : k_whh;
    const float* bih = lstm ? q_bih : k_bih;
    const float* bhh = lstm ? q_bhh : k_bhh;
    float* out = lstm ? q_out : k_out;
    float* hb = hbuf + lstm * 16384;
    int* subc = sub + ((lstm * 8 + grp) << 10);  // [t]
    int* mstc = mst + (lstm << 10);              // [t]

    const int wv = tid >> 6, lane = tid & 63;
    const int cg = lane & 3, bg = (lane >> 2) & 3, ks = lane >> 4;

    // ---- 32 named weight float4s ----
    float4 w00,w01,w02,w03,w04,w05,w06,w07;
    float4 w10,w11,w12,w13,w14,w15,w16,w17;
    float4 w20,w21,w22,w23,w24,w25,w26,w27;
    float4 w30,w31,w32,w33,w34,w35,w36,w37;
    {
        const float* Wsrc = (wv < 4) ? wih : whh;
        const int kb = (wv & 3) * 128 + ks * 32;
        const float4* p;
        p = (const float4*)(Wsrc + ((size_t)(0 * 512 + u0 + cg) << 9) + kb);
        w00=p[0];w01=p[1];w02=p[2];w03=p[3];w04=p[4];w05=p[5];w06=p[6];w07=p[7];
        p = (const float4*)(Wsrc + ((size_t)(1 * 512 + u0 + cg) << 9) + kb);
        w10=p[0];w11=p[1];w12=p[2];w13=p[3];w14=p[4];w15=p[5];w16=p[6];w17=p[7];
        p = (const float4*)(Wsrc + ((size_t)(2 * 512 + u0 + cg) << 9) + kb);
        w20=p[0];w21=p[1];w22=p[2];w23=p[3];w24=p[4];w25=p[5];w26=p[6];w27=p[7];
        p = (const float4*)(Wsrc + ((size_t)(3 * 512 + u0 + cg) << 9) + kb);
        w30=p[0];w31=p[1];w32=p[2];w33=p[3];w34=p[4];w35=p[5];w36=p[6];w37=p[7];
    }
    // ---- force VGPR residency: per-component launder (param V: avoid .w token clash) ----
    #define LNDR(V) asm volatile("" : "+v"(V.x), "+v"(V.y), "+v"(V.z), "+v"(V.w))
    LNDR(w00);LNDR(w01);LNDR(w02);LNDR(w03);LNDR(w04);LNDR(w05);LNDR(w06);LNDR(w07);
    LNDR(w10);LNDR(w11);LNDR(w12);LNDR(w13);LNDR(w14);LNDR(w15);LNDR(w16);LNDR(w17);
    LNDR(w20);LNDR(w21);LNDR(w22);LNDR(w23);LNDR(w24);LNDR(w25);LNDR(w26);LNDR(w27);
    LNDR(w30);LNDR(w31);LNDR(w32);LNDR(w33);LNDR(w34);LNDR(w35);LNDR(w36);LNDR(w37);
    #undef LNDR

    // vec: [xf 16 blocks | h 16 blocks], block = 32 k x 16 b = 128 float4, +2 pad -> 130
    __shared__ __align__(16) float4 vec4[4160];   // 66560 B
    __shared__ float part[16][16][33];            // [col][batch][s]
    __shared__ float gsum[256];                   // [col][batch]
    __shared__ int ready;                         // LDS release flag (wave4 -> waves 5-7)

    const int cu = tid & 3, cb = tid >> 2;        // finalize mapping (tid<64)
    float bI = 0.f, bF = 0.f, bG = 0.f, bO = 0.f, cst = 0.f;
    if (tid < 64) {
        bI = bih[0 * 512 + u0 + cu] + bhh[0 * 512 + u0 + cu];
        bF = bih[1 * 512 + u0 + cu] + bhh[1 * 512 + u0 + cu];
        bG = bih[2 * 512 + u0 + cu] + bhh[2 * 512 + u0 + cu];
        bO = bih[3 * 512 + u0 + cu] + bhh[3 * 512 + u0 + cu];
    }
    if (tid == 0) ready = 0;

    // xf prefetch for t=0 (ih waves own their slice: 8 float4/lane)
    float4 xf0{},xf1{},xf2{},xf3{},xf4{},xf5{},xf6{},xf7{};
    if (wv < 4) {
        const float4* xs = (const float4*)xf_t + (wv << 9) + lane;
        xf0=xs[0];  xf1=xs[64];  xf2=xs[128]; xf3=xs[192];
        xf4=xs[256];xf5=xs[320]; xf6=xs[384]; xf7=xs[448];
    }
    __syncthreads();   // ready init visible

    for (int t = 0; t < T_; ++t) {
        const int rb = t & 1;
        float4 a0{},a1{},a2{},a3{};
        const float4* vb;
        if (wv < 4) {
            // ---- ih wave: stage own xf slice, prefetch next, compute (overlaps hh wait) ----
            const int xb = wv * 520;  // wv*4 blocks * 130
            vec4[xb +   0 + lane] = xf0;
            vec4[xb +  64 + lane] = xf1;
            vec4[xb + 130 + lane] = xf2;
            vec4[xb + 194 + lane] = xf3;
            vec4[xb + 260 + lane] = xf4;
            vec4[xb + 324 + lane] = xf5;
            vec4[xb + 390 + lane] = xf6;
            vec4[xb + 454 + lane] = xf7;
            if (t + 1 < T_) {
                const float4* xs = (const float4*)(xf_t + ((size_t)(t + 1) << 13)) + (wv << 9) + lane;
                xf0=xs[0];  xf1=xs[64];  xf2=xs[128]; xf3=xs[192];
                xf4=xs[256];xf5=xs[320]; xf6=xs[384]; xf7=xs[448];
            }
            asm volatile("s_waitcnt lgkmcnt(0)" ::: "memory");  // cross-lane LDS visibility
            vb = vec4 + xb + ks * 130 + bg;
        } else {
            // ---- hh wave: wait for h_{t-1}, stage own h slice, compute ----
            if (t > 0) {
                if (wv == 4) {
                    while (__hip_atomic_load(&mstc[t - 1], __ATOMIC_RELAXED, __HIP_MEMORY_SCOPE_SYSTEM) < 8)
                        __builtin_amdgcn_s_sleep(2);
                    if (lane == 0)
                        __hip_atomic_store(&ready, t, __ATOMIC_RELAXED, __HIP_MEMORY_SCOPE_WORKGROUP);
                } else {
                    while (__hip_atomic_load(&ready, __ATOMIC_RELAXED, __HIP_MEMORY_SCOPE_WORKGROUP) < t)
                        __builtin_amdgcn_s_sleep(1);
                }
            }
            const float4* hp  = (const float4*)(hb + rb * 8192) + ((wv - 4) << 9) + lane;
            const float4* hp2 = hp + 256;
            float4 h0,h1,h2,h3,h4,h5,h6,h7;
            asm volatile(
                "global_load_dwordx4 %0, %8, off sc0 sc1\n\t"
                "global_load_dwordx4 %1, %8, off offset:1024 sc0 sc1\n\t"
                "global_load_dwordx4 %2, %8, off offset:2048 sc0 sc1\n\t"
                "global_load_dwordx4 %3, %8, off offset:3072 sc0 sc1\n\t"
                "global_load_dwordx4 %4, %9, off sc0 sc1\n\t"
                "global_load_dwordx4 %5, %9, off offset:1024 sc0 sc1\n\t"
                "global_load_dwordx4 %6, %9, off offset:2048 sc0 sc1\n\t"
                "global_load_dwordx4 %7, %9, off offset:3072 sc0 sc1\n\t"
                "s_waitcnt vmcnt(0)"
                : "=&v"(h0),"=&v"(h1),"=&v"(h2),"=&v"(h3),
                  "=&v"(h4),"=&v"(h5),"=&v"(h6),"=&v"(h7)
                : "v"(hp), "v"(hp2)
                : "memory");
            const int hbv = 2080 + (wv - 4) * 520;
            vec4[hbv +   0 + lane] = h0;
            vec4[hbv +  64 + lane] = h1;
            vec4[hbv + 130 + lane] = h2;
            vec4[hbv + 194 + lane] = h3;
            vec4[hbv + 260 + lane] = h4;
            vec4[hbv + 324 + lane] = h5;
            vec4[hbv + 390 + lane] = h6;
            vec4[hbv + 454 + lane] = h7;
            asm volatile("s_waitcnt lgkmcnt(0)" ::: "memory");
            vb = vec4 + hbv + ks * 130 + bg;
        }

        #define FMA4_(A, W) \
            A.x += W.x*v0.x + W.y*v1.x + W.z*v2.x + W.w*v3.x; \
            A.y += W.x*v0.y + W.y*v1.y + W.z*v2.y + W.w*v3.y; \
            A.z += W.x*v0.z + W.y*v1.z + W.z*v2.z + W.w*v3.z; \
            A.w += W.x*v0.w + W.y*v1.w + W.z*v2.w + W.w*v3.w;
        #define FSTEP(i, WA, WB, WC, WD) { \
            float4 v0 = vb[(i)*16], v1 = vb[(i)*16+4], v2 = vb[(i)*16+8], v3 = vb[(i)*16+12]; \
            FMA4_(a0, WA) FMA4_(a1, WB) FMA4_(a2, WC) FMA4_(a3, WD) }
        FSTEP(0, w00,w10,w20,w30)
        FSTEP(1, w01,w11,w21,w31)
        FSTEP(2, w02,w12,w22,w32)
        FSTEP(3, w03,w13,w23,w33)
        FSTEP(4, w04,w14,w24,w34)
        FSTEP(5, w05,w15,w25,w35)
        FSTEP(6, w06,w16,w26,w36)
        FSTEP(7, w07,w17,w27,w37)
        #undef FSTEP
        #undef FMA4_

        {
            const int s = wv * 4 + ks, c0 = cg * 4, bq = bg * 4;
            part[c0 + 0][bq + 0][s] = a0.x; part[c0 + 0][bq + 1][s] = a0.y;
            part[c0 + 0][bq + 2][s] = a0.z; part[c0 + 0][bq + 3][s] = a0.w;
            part[c0 + 1][bq + 0][s] = a1.x; part[c0 + 1][bq + 1][s] = a1.y;
            part[c0 + 1][bq + 2][s] = a1.z; part[c0 + 1][bq + 3][s] = a1.w;
            part[c0 + 2][bq + 0][s] = a2.x; part[c0 + 2][bq + 1][s] = a2.y;
            part[c0 + 2][bq + 2][s] = a2.z; part[c0 + 2][bq + 3][s] = a2.w;
            part[c0 + 3][bq + 0][s] = a3.x; part[c0 + 3][bq + 1][s] = a3.y;
            part[c0 + 3][bq + 2][s] = a3.z; part[c0 + 3][bq + 3][s] = a3.w;
        }
        __syncthreads();                       // part complete

        if (tid < 256) {                       // waves 0-3 reduce
            const int c = tid >> 4, b = tid & 15;
            float s2 = 0.f;
            #pragma unroll
            for (int ss = 0; ss < 32; ++ss) s2 += part[c][b][ss];
            gsum[c * 16 + b] = s2;
        }
        __syncthreads();                       // gsum ready (also: reduce reads done)

        if (tid < 64) {                        // wave 0 finalize + h store
            float gI = bI + gsum[(cu * 4 + 0) * 16 + cb];
            float gF = bF + gsum[(cu * 4 + 1) * 16 + cb];
            float gG = bG + gsum[(cu * 4 + 2) * 16 + cb];
            float gO = bO + gsum[(cu * 4 + 3) * 16 + cb];
            float ig = sigmoidf_(gI), fg = sigmoidf_(gF), gg = tanhf(gG), og = sigmoidf_(gO);
            cst = fg * cst + ig * gg;
            float h = og * tanhf(cst);
            __hip_atomic_store(&hb[((rb ^ 1) << 13) + ((u0 + cu) << 4) + cb], h,
                               __ATOMIC_RELAXED, __HIP_MEMORY_SCOPE_SYSTEM);
            out[((size_t)(cb * T_ + t) << 9) + (u0 + cu)] = h;
            asm volatile("s_waitcnt vmcnt(0)" ::: "memory");  // h at coherence point (wave 0)
        }
        if (tid == 0) {
            // arrival after wave-0 vmcnt(0): master==8 => all 128 WGs' h visible
            int old = __hip_atomic_fetch_add(&subc[t], 1, __ATOMIC_RELAXED, __HIP_MEMORY_SCOPE_AGENT);
            if (old == 15)
                __hip_atomic_fetch_add(&mstc[t], 1, __ATOMIC_RELAXED, __HIP_MEMORY_SCOPE_AGENT);
        }
        // no end-of-step barrier: next-iter hazards gated by poll/arrival chain (see header)
    }
}

// ---------------- attention pass 1: banded causal exp-scores -> normalized rows ----------------
__global__ __launch_bounds__(256)
void attn_scores(const float* __restrict__ qs, const float* __restrict__ kk,
                 float* __restrict__ attn_out)
{
    int t = blockIdx.x, b = blockIdx.y, tid = threadIdx.x;
    int jlo = t - ALEN; if (jlo < 0) jlo = 0;
    int cnt = t - jlo + 1;                       // <= 129
    __shared__ __align__(16) float qrow[512];
    __shared__ float sc[132];
    __shared__ float ssum;
    const float* qsr = qs + ((size_t)(b * T_ + t) << 9);
    qrow[tid] = qsr[tid];
    qrow[tid + 256] = qsr[tid + 256];
    __syncthreads();
    if (tid < cnt) {
        const float4* krow = (const float4*)(kk + ((size_t)(b * T_ + jlo + tid) << 9));
        const float4* q4 = (const float4*)qrow;
        float acc = 0.f;
        #pragma unroll 4
        for (int i = 0; i < 128; ++i) {
            float4 kv = krow[i]; float4 qv = q4[i];
            acc += kv.x * qv.x + kv.y * qv.y + kv.z * qv.z + kv.w * qv.w;
        }
        sc[tid] = expf(acc);                     // no max-subtraction (faithful to reference)
    }
    __syncthreads();
    if (tid < 64) {
        float s = 0.f;
        for (int j = tid; j < cnt; j += 64) s += sc[j];
        #pragma unroll
        for (int off = 32; off > 0; off >>= 1) s += __shfl_down(s, off);
        if (tid == 0) ssum = s + 1e-10f;
    }
    __syncthreads();
    float inv = 1.0f / ssum;
    float4* arow = (float4*)(attn_out + ((size_t)(b * T_ + t) << 10));
    int j0 = tid * 4;
    float4 v;
    v.x = (j0 + 0 >= jlo && j0 + 0 <= t) ? sc[j0 + 0 - jlo] * inv : 0.f;
    v.y = (j0 + 1 >= jlo && j0 + 1 <= t) ? sc[j0 + 1 - jlo] * inv : 0.f;
    v.z = (j0 + 2 >= jlo && j0 + 2 <= t) ? sc[j0 + 2 - jlo] * inv : 0.f;
    v.w = (j0 + 3 >= jlo && j0 + 3 <= t) ? sc[j0 + 3 - jlo] * inv : 0.f;
    arow[tid] = v;
}

// ---------------- attention pass 2: c = attn(normalized rows) @ k ----------------
__global__ __launch_bounds__(256)
void attn_ctx(const float* __restrict__ attn, const float* __restrict__ kk,
              float* __restrict__ c_out)
{
    int t = blockIdx.x, b = blockIdx.y, tid = threadIdx.x;
    int jlo = t - ALEN; if (jlo < 0) jlo = 0;
    int cnt = t - jlo + 1;
    __shared__ float sc[132];
    if (tid < cnt) sc[tid] = attn[((size_t)(b * T_ + t) << 10) + jlo + tid];
    __syncthreads();
    #pragma unroll
    for (int hh = 0; hh < 2; ++hh) {
        int h = tid + hh * 256;
        const float* kcol = kk + ((size_t)(b * T_ + jlo) << 9) + h;
        float acc = 0.f;
        #pragma unroll 4
        for (int jj = 0; jj < cnt; ++jj) acc += sc[jj] * kcol[(size_t)jj << 9];
        c_out[((size_t)(b * T_ + t) << 9) + h] = acc;
    }
}

extern "C" void kernel_launch(void* const* d_in, const int* in_sizes, int n_in,
                              void* d_out_v, int out_size, void* d_ws, size_t ws_size,
                              hipStream_t stream)
{
    const float* x       = (const float*)d_in[0];
    const float* feat_w  = (const float*)d_in[1];
    const float* feat_b  = (const float*)d_in[2];
    const float* k_w_ih  = (const float*)d_in[3];
    const float* k_w_hh  = (const float*)d_in[4];
    const float* k_b_ih  = (const float*)d_in[5];
    const float* k_b_hh  = (const float*)d_in[6];
    const float* q_w_ih  = (const float*)d_in[7];
    const float* q_w_hh  = (const float*)d_in[8];
    const float* q_b_ih  = (const float*)d_in[9];
    const float* q_b_hh  = (const float*)d_in[10];
    const float* score_w = (const float*)d_in[11];
    const float* enh_w   = (const float*)d_in[12];
    const float* enh_b   = (const float*)d_in[13];
    const float* mask_w  = (const float*)d_in[14];
    const float* mask_b  = (const float*)d_in[15];
    float* out = (float*)d_out_v;
    float* ws  = (float*)d_ws;

    if (ws_size < WS_NEED * sizeof(float)) return;  // clean fail if ws too small

    float* bufA = ws + OFF_A;   // xf_t -> qs -> c
    float* bufB = ws + OFF_B;   // k -> enh
    float* bufC = ws + OFF_C;   // q
    float* hbuf = ws + OFF_HB;
    int*   sub  = (int*)(ws + OFF_SUB);
    int*   mst  = (int*)(ws + OFF_MST);

    // zero h double-buffers + all barrier counters (contiguous region)
    hipMemsetAsync(hbuf, 0, (32768 + 16384 + 2048) * sizeof(float), stream);

    dim3 blk(256);
    // xf_t[t][n][b] = x @ feat_w^T + feat_b   (transposed store for LSTM staging)
    gemm_kernel<3><<<dim3(8, 256), blk, 0, stream>>>(x, nullptr, F_, feat_w, feat_b, nullptr, nullptr, bufA, BT, H_, F_);
    // fused recurrence, both LSTMs (w_ih + w_hh + biases inside)
    lstm_fused<<<dim3(LSTM_NWG), dim3(512), 0, stream>>>(bufA,
        k_w_ih, k_w_hh, k_b_ih, k_b_hh, q_w_ih, q_w_hh, q_b_ih, q_b_hh,
        bufB, bufC, hbuf, sub, mst);
    // qs = q @ score_w^T  (overwrites xf_t, dead)
    gemm_kernel<0><<<dim3(8, 256), blk, 0, stream>>>(bufC, nullptr, H_, score_w, nullptr, nullptr, nullptr, bufA, BT, H_, H_);
    // attn rows -> d_out tail
    attn_scores<<<dim3(T_, B_), blk, 0, stream>>>(bufA, bufB, out + (size_t)BT * F_);
    // c = attn @ k  (overwrites qs, dead)
    attn_ctx<<<dim3(T_, B_), blk, 0, stream>>>(out + (size_t)BT * F_, bufB, bufA);
    // enh = tanh(concat(c, q) @ enh_w^T + enh_b)  (overwrites k, dead)
    gemm_kernel<1><<<dim3(8, 256), blk, 0, stream>>>(bufA, bufC, H_, enh_w, enh_b, nullptr, nullptr, bufB, BT, H_, 2 * H_);
    // out = sigmoid(enh @ mask_w^T + mask_b) * x
    gemm_kernel<2><<<dim3(5, 256), blk, 0, stream>>>(bufB, nullptr, H_, mask_w, mask_b, nullptr, x, out, BT, F_, H_);
}